// Round 8
// baseline (22014.632 us; speedup 1.0000x reference)
//
#include <hip/hip_runtime.h>
#include <math.h>
#include <limits.h>

#define T_DIM 128
#define B_DIM 256
#define X_DIMC 256
#define H_DIMC 1024
#define Z_DIMC 128
#define EPSF 1.1920929e-07f
#define HALF_LOG_2PI 0.91893853320467274f
#define NBLK 768
#define NPB (NBLK / 64)

typedef float f32x4 __attribute__((ext_vector_type(4)));
typedef short bf16x8 __attribute__((ext_vector_type(8)));
typedef int int4v __attribute__((ext_vector_type(4)));
typedef int int2v __attribute__((ext_vector_type(2)));

struct Seg { int n_end; int kbeg; int kend; const float* bias; int act;
             float* of32; int ld32; short* ob16; int ld16; };
struct Segs { Seg s[4]; };

__host__ __device__ static inline Seg dseg(int n_end, int kbeg, int kend,
    const float* bias, int act, float* of32, int ld32, short* ob16, int ld16)
{
    Seg s; s.n_end = n_end; s.kbeg = kbeg; s.kend = kend; s.bias = bias;
    s.act = act; s.of32 = of32; s.ld32 = ld32; s.ob16 = ob16; s.ld16 = ld16;
    return s;
}
__host__ __device__ static inline Seg dsegend()
{ return dseg(INT_MAX, 0, 64, nullptr, 0, nullptr, 0, nullptr, 0); }

__device__ __forceinline__ short f2bf(float f) {
    unsigned u = __builtin_bit_cast(unsigned, f);
    u += 0x7fffu + ((u >> 16) & 1u);
    return (short)(u >> 16);
}
__device__ __forceinline__ int packbf2(float a, float b) {
    return (int)((((unsigned)(unsigned short)f2bf(b)) << 16) |
                 (unsigned)(unsigned short)f2bf(a));
}
__device__ __forceinline__ float act_apply(float x, int act) {
    if (act == 1) return fmaxf(x, 0.f);
    if (act == 2) return x > 0.f ? x + log1pf(expf(-x)) : log1pf(expf(x));
    return x;
}
// weights: cached (read-only during kernel -> never stale)
__device__ __forceinline__ void gload16(const short* g, short* l) {
    __builtin_amdgcn_global_load_lds(
        (const __attribute__((address_space(1))) void*)g,
        (__attribute__((address_space(3))) void*)l, 16, 0, 0);
}
// activations: sc0|sc1 -> coherent at L3 (proven r6/r7)
__device__ __forceinline__ void gload16a(const short* g, short* l) {
    __builtin_amdgcn_global_load_lds(
        (const __attribute__((address_space(1))) void*)g,
        (__attribute__((address_space(3))) void*)l, 16, 0, 17);
}
__device__ __forceinline__ float ldf(const float* p) {
    return __hip_atomic_load(p, __ATOMIC_RELAXED, __HIP_MEMORY_SCOPE_AGENT);
}
// ---- wide coherent loads/stores ----
__device__ __forceinline__ void ldg4x4(const float* p0, const float* p1,
                                       const float* p2, const float* p3,
                                       f32x4& a, f32x4& b, f32x4& c, f32x4& d) {
    asm volatile(
        "global_load_dwordx4 %0, %4, off sc0 sc1\n\t"
        "global_load_dwordx4 %1, %5, off sc0 sc1\n\t"
        "global_load_dwordx4 %2, %6, off sc0 sc1\n\t"
        "global_load_dwordx4 %3, %7, off sc0 sc1\n\t"
        "s_waitcnt vmcnt(0)"
        : "=&v"(a), "=&v"(b), "=&v"(c), "=&v"(d)
        : "v"(p0), "v"(p1), "v"(p2), "v"(p3) : "memory");
}
__device__ __forceinline__ void stg4f(float* p, f32x4 v) {
    asm volatile("global_store_dwordx4 %0, %1, off sc0 sc1"
                 :: "v"(p), "v"(v) : "memory");
}
__device__ __forceinline__ void stg4i(short* p, int4v v) {
    asm volatile("global_store_dwordx4 %0, %1, off sc0 sc1"
                 :: "v"(p), "v"(v) : "memory");
}
__device__ __forceinline__ void stg2i(short* p, int2v v) {
    asm volatile("global_store_dwordx2 %0, %1, off sc0 sc1"
                 :: "v"(p), "v"(v) : "memory");
}

// ---- fence-free tree grid barrier (r6/r7-proven) ----
__device__ __forceinline__ void gridbar(unsigned* bar, int phase) {
    asm volatile("s_waitcnt vmcnt(0)" ::: "memory");
    __syncthreads();
    if (threadIdx.x == 0) {
        unsigned* leaf = bar + ((blockIdx.x & 63) << 5);
        unsigned* root = bar + (64 << 5);
        unsigned* gen  = root + 32;
        unsigned old = __hip_atomic_fetch_add(leaf, 1u, __ATOMIC_RELAXED,
                                              __HIP_MEMORY_SCOPE_AGENT);
        if (((old + 1u) % (unsigned)NPB) == 0u) {
            unsigned r = __hip_atomic_fetch_add(root, 1u, __ATOMIC_RELAXED,
                                                __HIP_MEMORY_SCOPE_AGENT);
            if (((r + 1u) & 63u) == 0u)
                __hip_atomic_store(gen, (r + 1u) >> 6, __ATOMIC_RELAXED,
                                   __HIP_MEMORY_SCOPE_AGENT);
        }
        while ((int)__hip_atomic_load(gen, __ATOMIC_RELAXED,
                                      __HIP_MEMORY_SCOPE_AGENT) < phase)
            __builtin_amdgcn_s_sleep(2);
    }
    __syncthreads();
}

// ---- 64x128 GEMM tile: depth-2 prefetch, counted vmcnt, XOR swizzle,
//      bank-safe LDS-bounce vectorized epilogue (stride 133) ----
__device__ __forceinline__ void gemm_tile(
    short* __restrict__ smem, int bm0, int bn0,
    const short* __restrict__ A0, int lda0,
    const short* __restrict__ A1, int lda1,
    const short* __restrict__ A2, int lda2,
    int ks1, int ks2,
    const short* __restrict__ BT, int ldb, const Segs& segs)
{
    short* As = smem;            // [2][64][64]
    short* Bs = smem + 8192;     // [2][128][64]
    const int tid = threadIdx.x, lane = tid & 63, wid = tid >> 6;
    __syncthreads();             // previous unit's LDS use complete
    Seg sg; int n0;
    if      (bn0 < segs.s[0].n_end) { sg = segs.s[0]; n0 = 0; }
    else if (bn0 < segs.s[1].n_end) { sg = segs.s[1]; n0 = segs.s[0].n_end; }
    else if (bn0 < segs.s[2].n_end) { sg = segs.s[2]; n0 = segs.s[1].n_end; }
    else                            { sg = segs.s[3]; n0 = segs.s[2].n_end; }
    const int nit = (sg.kend - sg.kbeg) >> 6;
    const int row8 = lane >> 3;
    const int kc = ((lane & 7) ^ row8) << 3;   // pre-swizzled source col
    const int ar = (wid << 4) + row8;          // A rows: ar, ar+8
    const int br = (wid << 5) + row8;          // B rows: br, +8, +16, +24

    auto srcA = [&](int r, int gk) -> const short* {
        return (gk < ks1) ? A0 + (size_t)(bm0 + r) * lda0 + gk
             : (gk < ks2) ? A1 + (size_t)(bm0 + r) * lda1 + (gk - ks1)
                          : A2 + (size_t)(bm0 + r) * lda2 + (gk - ks2);
    };
    auto stage = [&](int p, int it) {
        const int gk = sg.kbeg + (it << 6) + kc;
        gload16a(srcA(ar, gk),     As + p * 4096 + ((wid << 4) + 0) * 64);
        gload16a(srcA(ar + 8, gk), As + p * 4096 + ((wid << 4) + 8) * 64);
        gload16(BT + (size_t)(bn0 + br) * ldb + gk,      Bs + p * 8192 + ((wid << 5) + 0) * 64);
        gload16(BT + (size_t)(bn0 + br + 8) * ldb + gk,  Bs + p * 8192 + ((wid << 5) + 8) * 64);
        gload16(BT + (size_t)(bn0 + br + 16) * ldb + gk, Bs + p * 8192 + ((wid << 5) + 16) * 64);
        gload16(BT + (size_t)(bn0 + br + 24) * ldb + gk, Bs + p * 8192 + ((wid << 5) + 24) * 64);
    };

    const int l15 = lane & 15, lg = lane >> 4;
    const int wm = (wid >> 1) << 5, wn = (wid & 1) << 6;
    const int swz = (l15 & 7) << 3;
    const int cA = (lg << 3) ^ swz;
    const int cB = (32 + (lg << 3)) ^ swz;
    f32x4 acc[2][4] = {};

    stage(0, 0);
    if (nit > 1) stage(1, 1);
    int p = 0;
    for (int it = 0; it < nit; ++it) {
        const int rem = nit - 1 - it;
        if (rem >= 1) asm volatile("s_waitcnt vmcnt(6)" ::: "memory");
        else          asm volatile("s_waitcnt vmcnt(0)" ::: "memory");
        asm volatile("s_barrier" ::: "memory");
        const short* Ap = As + p * 4096;
        const short* Bp = Bs + p * 8192;
#pragma unroll
        for (int h = 0; h < 2; ++h) {
            const int cc = h ? cB : cA;
            bf16x8 a0 = *(const bf16x8*)(Ap + (wm + l15) * 64 + cc);
            bf16x8 a1 = *(const bf16x8*)(Ap + (wm + 16 + l15) * 64 + cc);
            bf16x8 b0 = *(const bf16x8*)(Bp + (wn + l15) * 64 + cc);
            bf16x8 b1 = *(const bf16x8*)(Bp + (wn + 16 + l15) * 64 + cc);
            bf16x8 b2 = *(const bf16x8*)(Bp + (wn + 32 + l15) * 64 + cc);
            bf16x8 b3 = *(const bf16x8*)(Bp + (wn + 48 + l15) * 64 + cc);
            acc[0][0] = __builtin_amdgcn_mfma_f32_16x16x32_bf16(a0, b0, acc[0][0], 0, 0, 0);
            acc[0][1] = __builtin_amdgcn_mfma_f32_16x16x32_bf16(a0, b1, acc[0][1], 0, 0, 0);
            acc[0][2] = __builtin_amdgcn_mfma_f32_16x16x32_bf16(a0, b2, acc[0][2], 0, 0, 0);
            acc[0][3] = __builtin_amdgcn_mfma_f32_16x16x32_bf16(a0, b3, acc[0][3], 0, 0, 0);
            acc[1][0] = __builtin_amdgcn_mfma_f32_16x16x32_bf16(a1, b0, acc[1][0], 0, 0, 0);
            acc[1][1] = __builtin_amdgcn_mfma_f32_16x16x32_bf16(a1, b1, acc[1][1], 0, 0, 0);
            acc[1][2] = __builtin_amdgcn_mfma_f32_16x16x32_bf16(a1, b2, acc[1][2], 0, 0, 0);
            acc[1][3] = __builtin_amdgcn_mfma_f32_16x16x32_bf16(a1, b3, acc[1][3], 0, 0, 0);
        }
        if (rem >= 2) {
            asm volatile("s_waitcnt lgkmcnt(0)\n\ts_barrier" ::: "memory");
            stage(p, it + 2);
        }
        p ^= 1;
    }

    // epilogue: bounce acc tile through LDS -> row-contiguous wide stores
    __syncthreads();
    float* bounce = (float*)smem;     // [64][133], odd stride -> bank-safe
#pragma unroll
    for (int i = 0; i < 2; ++i)
#pragma unroll
        for (int j = 0; j < 4; ++j)
#pragma unroll
            for (int r = 0; r < 4; ++r)
                bounce[(wm + i * 16 + (lg << 2) + r) * 133 + wn + j * 16 + l15] =
                    acc[i][j][r];
    __syncthreads();
    const int brow = tid >> 2, bc0 = (tid & 3) << 5;   // 32 cols/thread
    const int gm = bm0 + brow;
    const int cn0 = bn0 + bc0 - n0;
#pragma unroll
    for (int c = 0; c < 4; ++c) {
        const int cn = cn0 + (c << 3);
        const float* bp = bounce + brow * 133 + bc0 + (c << 3);
        const f32x4 bb0 = *(const f32x4*)(sg.bias + cn);
        const f32x4 bb1 = *(const f32x4*)(sg.bias + cn + 4);
        f32x4 v0, v1;
#pragma unroll
        for (int q = 0; q < 4; ++q) {
            v0[q] = act_apply(bp[q] + bb0[q], sg.act);
            v1[q] = act_apply(bp[q + 4] + bb1[q], sg.act);
        }
        if (sg.of32) {
            float* qp = sg.of32 + (size_t)gm * sg.ld32 + cn;
            stg4f(qp, v0); stg4f(qp + 4, v1);
        }
        if (sg.ob16) {
            int4v pk;
            pk[0] = packbf2(v0[0], v0[1]); pk[1] = packbf2(v0[2], v0[3]);
            pk[2] = packbf2(v1[0], v1[1]); pk[3] = packbf2(v1[2], v1[3]);
            stg4i(sg.ob16 + (size_t)gm * sg.ld16 + cn, pk);
        }
    }
}

// ---- z-GEMM tile (64x64, K=128): A = em + eps*es on the fly ----
__device__ __forceinline__ void z_tile(
    short* __restrict__ smem, int bm0, int bn0,
    const float* __restrict__ zm, const float* __restrict__ zs,
    const float* __restrict__ ze,
    const short* __restrict__ BT, const float* __restrict__ bias,
    short* __restrict__ outb)
{
    short* Az = smem;            // [64][136]
    short* Bz = smem + 8704;
    const int tid = threadIdx.x, lane = tid & 63, wid = tid >> 6;
    __syncthreads();
    const int r = tid >> 2, c8 = (tid & 3) << 3;
#pragma unroll
    for (int s = 0; s < 4; ++s) {
        const int col = c8 + s * 32;
        const size_t base = (size_t)(bm0 + r) * 128 + col;
        f32x4 m0, m1, s0, s1;
        ldg4x4(zm + base, zm + base + 4, zs + base, zs + base + 4, m0, m1, s0, s1);
        const f32x4 e0 = *(const f32x4*)(ze + base);
        const f32x4 e1 = *(const f32x4*)(ze + base + 4);
        short tmp[8];
#pragma unroll
        for (int q = 0; q < 4; ++q) {
            tmp[q]     = f2bf(fmaf(e0[q], s0[q], m0[q]));
            tmp[q + 4] = f2bf(fmaf(e1[q], s1[q], m1[q]));
        }
        *(bf16x8*)(Az + r * 136 + col) = *(bf16x8*)tmp;
        *(bf16x8*)(Bz + r * 136 + col) =
            *(const bf16x8*)(BT + (size_t)(bn0 + r) * 128 + col);
    }
    __syncthreads();
    const int l15 = lane & 15, lg = lane >> 4;
    const int wm = (wid >> 1) << 5, wn = (wid & 1) << 5;
    f32x4 acc[2][2] = {};
#pragma unroll
    for (int s = 0; s < 4; ++s) {
        bf16x8 af0 = *(const bf16x8*)(Az + (wm + l15) * 136 + (lg << 3) + s * 32);
        bf16x8 af1 = *(const bf16x8*)(Az + (wm + 16 + l15) * 136 + (lg << 3) + s * 32);
        bf16x8 bg0 = *(const bf16x8*)(Bz + (wn + l15) * 136 + (lg << 3) + s * 32);
        bf16x8 bg1 = *(const bf16x8*)(Bz + (wn + 16 + l15) * 136 + (lg << 3) + s * 32);
        acc[0][0] = __builtin_amdgcn_mfma_f32_16x16x32_bf16(af0, bg0, acc[0][0], 0, 0, 0);
        acc[0][1] = __builtin_amdgcn_mfma_f32_16x16x32_bf16(af0, bg1, acc[0][1], 0, 0, 0);
        acc[1][0] = __builtin_amdgcn_mfma_f32_16x16x32_bf16(af1, bg0, acc[1][0], 0, 0, 0);
        acc[1][1] = __builtin_amdgcn_mfma_f32_16x16x32_bf16(af1, bg1, acc[1][1], 0, 0, 0);
    }
    __syncthreads();
    float* bounce = (float*)smem;     // [64][69] odd-ish stride
#pragma unroll
    for (int j = 0; j < 2; ++j)
#pragma unroll
        for (int i = 0; i < 2; ++i)
#pragma unroll
            for (int rr = 0; rr < 4; ++rr)
                bounce[(wm + i * 16 + (lg << 2) + rr) * 69 + wn + j * 16 + l15] =
                    acc[i][j][rr];
    __syncthreads();
    const int brow = tid >> 2, bc0 = (tid & 3) << 4;   // 16 cols/thread
    const int gm = bm0 + brow, gn = bn0 + bc0;
#pragma unroll
    for (int c = 0; c < 2; ++c) {
        const float* bp = bounce + brow * 69 + bc0 + (c << 3);
        const f32x4 bb0 = *(const f32x4*)(bias + gn + (c << 3));
        const f32x4 bb1 = *(const f32x4*)(bias + gn + (c << 3) + 4);
        int4v pk;
        pk[0] = packbf2(fmaxf(bp[0] + bb0[0], 0.f), fmaxf(bp[1] + bb0[1], 0.f));
        pk[1] = packbf2(fmaxf(bp[2] + bb0[2], 0.f), fmaxf(bp[3] + bb0[3], 0.f));
        pk[2] = packbf2(fmaxf(bp[4] + bb1[0], 0.f), fmaxf(bp[5] + bb1[1], 0.f));
        pk[3] = packbf2(fmaxf(bp[6] + bb1[2], 0.f), fmaxf(bp[7] + bb1[3], 0.f));
        stg4i(outb + (size_t)gm * 1024 + gn + (c << 3), pk);
    }
}

// vectorized GRU: thread handles 4 consecutive j
__device__ __forceinline__ void gru_unit(int uid, int tid,
    const float* __restrict__ gi, const float* __restrict__ gh,
    const float* __restrict__ h, float* __restrict__ hn, short* __restrict__ hnb)
{
    const int i = (uid * 256 + tid) << 2;
    const int b = i >> 10, j = i & 1023;
    const float* pgi = gi + (size_t)b * 3072 + j;
    const float* pgh = gh + (size_t)b * 3072 + j;
    f32x4 ir, iz, in_, hr, hz, hn_, hv;
    asm volatile(
        "global_load_dwordx4 %0, %7, off sc0 sc1\n\t"
        "global_load_dwordx4 %1, %8, off sc0 sc1\n\t"
        "global_load_dwordx4 %2, %9, off sc0 sc1\n\t"
        "global_load_dwordx4 %3, %10, off sc0 sc1\n\t"
        "global_load_dwordx4 %4, %11, off sc0 sc1\n\t"
        "global_load_dwordx4 %5, %12, off sc0 sc1\n\t"
        "global_load_dwordx4 %6, %13, off sc0 sc1\n\t"
        "s_waitcnt vmcnt(0)"
        : "=&v"(ir), "=&v"(iz), "=&v"(in_), "=&v"(hr), "=&v"(hz), "=&v"(hn_), "=&v"(hv)
        : "v"(pgi), "v"(pgi + 1024), "v"(pgi + 2048),
          "v"(pgh), "v"(pgh + 1024), "v"(pgh + 2048), "v"(h + i)
        : "memory");
    f32x4 out;
    short hb4[4];
#pragma unroll
    for (int q = 0; q < 4; ++q) {
        const float rr = 1.f / (1.f + expf(-(ir[q] + hr[q])));
        const float uu = 1.f / (1.f + expf(-(iz[q] + hz[q])));
        const float nn = tanhf(in_[q] + rr * hn_[q]);
        const float v = (1.f - uu) * nn + uu * hv[q];
        out[q] = v; hb4[q] = f2bf(v);
    }
    stg4f(hn + i, out);
    int2v pk;
    pk[0] = (int)((((unsigned)(unsigned short)hb4[1]) << 16) | (unsigned)(unsigned short)hb4[0]);
    pk[1] = (int)((((unsigned)(unsigned short)hb4[3]) << 16) | (unsigned)(unsigned short)hb4[2]);
    stg2i(hnb + i, pk);
}

// r6-proven scalar loss: uid in [0,384): [0,128) kld, [128,384) nll
__device__ __forceinline__ void loss_unit(int uid, int tid,
    const float* __restrict__ em, const float* __restrict__ es,
    const float* __restrict__ pm, const float* __restrict__ ps,
    const float* __restrict__ xt, const float* __restrict__ dm,
    const float* __restrict__ ds, float* __restrict__ outp, float* sred)
{
    const int KB = (B_DIM * Z_DIMC) / 256;  // 128
    float v; int target;
    if (uid < KB) {
        const int i = uid * 256 + tid;
        const float esv = ldf(es + i), psv = ldf(ps + i);
        const float dmn = ldf(em + i) - ldf(pm + i);
        v = 0.5f * (2.f * logf(psv + EPSF) - 2.f * logf(esv + EPSF) +
                    (esv * esv + dmn * dmn) / (psv * psv) - 1.f);
        target = 0;
    } else {
        const int i = (uid - KB) * 256 + tid;
        const float d = ldf(ds + i);
        const float diff = xt[i] - ldf(dm + i);
        v = logf(d + EPSF) + HALF_LOG_2PI + diff * diff / (2.f * d * d);
        target = 1;
    }
    for (int o = 32; o > 0; o >>= 1) v += __shfl_down(v, o);
    if ((tid & 63) == 0) sred[tid >> 6] = v;
    __syncthreads();
    if (tid == 0) atomicAdd(outp + target, sred[0] + sred[1] + sred[2] + sred[3]);
    __syncthreads();
}

struct PP {
    const short* xb; const float* x; const float* eps;
    const short *WTpx, *WT1, *WT2, *WTpz, *WT4, *WT56;
    const float *bpx, *benc, *bpr, *bhh, *bem, *bes, *bpz, *bdec, *bih,
                *bpm, *bps, *bdm, *bds;
    float *hf0, *hf1; short *hb0, *hb1;
    short *enc_b, *prior_b, *phi_zb, *dec_b;
    short *phiXb, *phiXs;
    float *ghb, *gib, *pmb, *psb;
    float *kld, *em, *es, *dm, *ds;
    unsigned* bar; int big;
};

__global__ __launch_bounds__(256, 3) void vrnn_k(PP p)
{
    __shared__ short smem[24576];   // 48KB staging / bounce union -> 3 blocks/CU
    __shared__ float sred[4];
    const int G = gridDim.x, bid = blockIdx.x, tid = threadIdx.x;
    const int BIGK = 1 << 30;
    int ph = 0;

    Segs sx;
    sx.s[0] = dseg(1024, 0, 256, p.bpx, 1, nullptr, 0, p.big ? p.phiXb : p.phiXs, 1024);
    sx.s[1] = dsegend(); sx.s[2] = dsegend(); sx.s[3] = dsegend();

    if (p.big) {  // stage 0: phi_x for all T  (512 m-tiles x 8 n-tiles)
        for (int u = bid; u < 512 * 8; u += G)
            gemm_tile(smem, (u & 511) << 6, (u >> 9) << 7,
                      p.xb, 256, p.xb, 256, p.xb, 256, BIGK, BIGK,
                      p.WTpx, 256, sx);
        gridbar(p.bar, ++ph);
    }

    for (int t = 0; t < T_DIM; ++t) {
        float* hcur = (t & 1) ? p.hf1 : p.hf0;
        float* hnxt = (t & 1) ? p.hf0 : p.hf1;
        const short* hbc = (t & 1) ? p.hb1 : p.hb0;
        short* hbn = (t & 1) ? p.hb0 : p.hb1;
        const short* phiXt = p.big ? p.phiXb + (size_t)t * B_DIM * H_DIMC : p.phiXs;
        float* em_t = p.em + (size_t)t * B_DIM * Z_DIMC;
        float* es_t = p.es + (size_t)t * B_DIM * Z_DIMC;
        float* dm_t = p.dm + (size_t)t * B_DIM * X_DIMC;
        float* ds_t = p.ds + (size_t)t * B_DIM * X_DIMC;
        const float* eps_t = p.eps + (size_t)t * B_DIM * Z_DIMC;

        if (!p.big) {
            for (int u = bid; u < 32; u += G)
                gemm_tile(smem, (u & 3) << 6, (u >> 2) << 7,
                          p.xb + (size_t)t * B_DIM * X_DIMC, 256,
                          p.xb, 256, p.xb, 256, BIGK, BIGK, p.WTpx, 256, sx);
            gridbar(p.bar, ++ph);
        }
        // Stage A: G1 [phiX|h] -> enc | prior | gh ; + loss(t-1) (scalar)
        {
            Segs g1;
            g1.s[0] = dseg(1024, 0, 2048, p.benc, 1, nullptr, 0, p.enc_b, 1024);
            g1.s[1] = dseg(2048, 1024, 2048, p.bpr, 1, nullptr, 0, p.prior_b, 1024);
            g1.s[2] = dseg(5120, 1024, 2048, p.bhh, 0, p.ghb, 3 * H_DIMC, nullptr, 0);
            g1.s[3] = dsegend();
            const int tp = t - 1;
            const int nA = 160 + (t > 0 ? 384 : 0);
            for (int u = bid; u < nA; u += G) {
                if (u < 160)
                    gemm_tile(smem, (u & 3) << 6, (u >> 2) << 7,
                              phiXt, 1024, hbc, 1024, hbc, 1024, 1024, BIGK,
                              p.WT1, 2048, g1);
                else
                    loss_unit(u - 160, tid,
                              p.em + (size_t)tp * B_DIM * Z_DIMC,
                              p.es + (size_t)tp * B_DIM * Z_DIMC,
                              p.pmb, p.psb,
                              p.x + (size_t)tp * B_DIM * X_DIMC,
                              p.dm + (size_t)tp * B_DIM * X_DIMC,
                              p.ds + (size_t)tp * B_DIM * X_DIMC,
                              p.kld, sred);
            }
            gridbar(p.bar, ++ph);
        }
        // Stage B: G2 enc -> em | es(softplus) (direct to d_out)
        {
            Segs g2;
            g2.s[0] = dseg(128, 0, 1024, p.bem, 0, em_t, 128, nullptr, 0);
            g2.s[1] = dseg(256, 0, 1024, p.bes, 2, es_t, 128, nullptr, 0);
            g2.s[2] = dsegend(); g2.s[3] = dsegend();
            for (int u = bid; u < 8; u += G)
                gemm_tile(smem, (u & 3) << 6, (u >> 2) << 7,
                          p.enc_b, 1024, p.enc_b, 1024, p.enc_b, 1024, BIGK, BIGK,
                          p.WT2, 1024, g2);
            gridbar(p.bar, ++ph);
        }
        // Stage C: z = em + eps*es -> phi_z(relu)
        for (int u = bid; u < 64; u += G)
            z_tile(smem, (u & 3) << 6, (u >> 2) << 6,
                   em_t, es_t, eps_t, p.WTpz, p.bpz, p.phi_zb);
        gridbar(p.bar, ++ph);
        // Stage D: G4 [phiX|phi_z|h] -> dec | gi
        {
            Segs g4;
            g4.s[0] = dseg(1024, 1024, 3072, p.bdec, 1, nullptr, 0, p.dec_b, 1024);
            g4.s[1] = dseg(4096, 0, 2048, p.bih, 0, p.gib, 3 * H_DIMC, nullptr, 0);
            g4.s[2] = dsegend(); g4.s[3] = dsegend();
            for (int u = bid; u < 128; u += G)
                gemm_tile(smem, (u & 3) << 6, (u >> 2) << 7,
                          phiXt, 1024, p.phi_zb, 1024, hbc, 1024, 1024, 2048,
                          p.WT4, 3072, g4);
            gridbar(p.bar, ++ph);
        }
        // Stage E: G56 [prior|dec] -> pm|ps|dm|ds ; + GRU combine (wide)
        {
            Segs g5;
            g5.s[0] = dseg(128, 0, 1024, p.bpm, 0, p.pmb, 128, nullptr, 0);
            g5.s[1] = dseg(256, 0, 1024, p.bps, 2, p.psb, 128, nullptr, 0);
            g5.s[2] = dseg(512, 1024, 2048, p.bdm, 0, dm_t, 256, nullptr, 0);
            g5.s[3] = dseg(768, 1024, 2048, p.bds, 2, ds_t, 256, nullptr, 0);
            for (int u = bid; u < 24 + 256; u += G) {
                if (u < 24)
                    gemm_tile(smem, (u & 3) << 6, (u >> 2) << 7,
                              p.prior_b, 1024, p.dec_b, 1024, p.dec_b, 1024,
                              1024, BIGK, p.WT56, 2048, g5);
                else
                    gru_unit(u - 24, tid, p.gib, p.ghb, hcur, hnxt, hbn);
            }
            gridbar(p.bar, ++ph);
        }
    }
    // final loss for t = T-1
    {
        const int tp = T_DIM - 1;
        for (int u = bid; u < 384; u += G)
            loss_unit(u, tid,
                      p.em + (size_t)tp * B_DIM * Z_DIMC,
                      p.es + (size_t)tp * B_DIM * Z_DIMC,
                      p.pmb, p.psb,
                      p.x + (size_t)tp * B_DIM * X_DIMC,
                      p.dm + (size_t)tp * B_DIM * X_DIMC,
                      p.ds + (size_t)tp * B_DIM * X_DIMC,
                      p.kld, sred);
    }
}

// ---- prologue kernels ----
__global__ void packT_k(const float* __restrict__ src, int ldsr,
                        short* __restrict__ dst, int ldd, int n0, int k0)
{
    __shared__ float tile[32][33];
    const int bx = blockIdx.x * 32, by = blockIdx.y * 32;
    const int tx = threadIdx.x, ty = threadIdx.y;  // (32,8)
    for (int i = ty; i < 32; i += 8)
        tile[i][tx] = src[(size_t)(by + i) * ldsr + bx + tx];
    __syncthreads();
    for (int i = ty; i < 32; i += 8)
        dst[(size_t)(n0 + bx + i) * ldd + k0 + by + tx] = f2bf(tile[tx][i]);
}

__global__ void packD_k(const float* __restrict__ src, int ldsr,
                        short* __restrict__ dst, int ldd, int n0, int k0, int kr)
{
    const int idx = blockIdx.x * 256 + threadIdx.x;
    const int n = idx / kr, k = idx % kr;
    dst[(size_t)(n0 + n) * ldd + k0 + k] = f2bf(src[(size_t)n * ldsr + k]);
}

__global__ void cvtx_k(const float* __restrict__ x, short* __restrict__ xb)
{
    const int i = blockIdx.x * 256 + threadIdx.x;
    float4 v = ((const float4*)x)[i];
    short4 s;
    s.x = f2bf(v.x); s.y = f2bf(v.y); s.z = f2bf(v.z); s.w = f2bf(v.w);
    ((short4*)xb)[i] = s;
}

__global__ void hinit_k(const float* __restrict__ h0, float* __restrict__ hf,
                        short* __restrict__ hb)
{
    const int i = blockIdx.x * 256 + threadIdx.x;
    const float v = h0[i];
    hf[i] = v; hb[i] = f2bf(v);
}

__global__ void init_k(unsigned* bar, float* kn)
{
    for (int i = threadIdx.x; i < 64 * 32 + 64; i += 256) bar[i] = 0u;
    if (threadIdx.x < 2) kn[threadIdx.x] = 0.f;
}

extern "C" void kernel_launch(void* const* d_in, const int* in_sizes, int n_in,
                              void* d_out_v, int out_size, void* d_ws, size_t ws_size,
                              hipStream_t stream)
{
    (void)in_sizes; (void)n_in; (void)out_size;
    const float* x    = (const float*)d_in[0];
    const float* h0   = (const float*)d_in[1];
    const float* eps  = (const float*)d_in[2];
    const float* Wpx  = (const float*)d_in[3];
    const float* bpx  = (const float*)d_in[4];
    const float* Wpz  = (const float*)d_in[5];
    const float* bpz  = (const float*)d_in[6];
    const float* Wenc = (const float*)d_in[7];
    const float* benc = (const float*)d_in[8];
    const float* Wem  = (const float*)d_in[9];
    const float* bem  = (const float*)d_in[10];
    const float* Wes  = (const float*)d_in[11];
    const float* bes  = (const float*)d_in[12];
    const float* Wpr  = (const float*)d_in[13];
    const float* bpr  = (const float*)d_in[14];
    const float* Wpm  = (const float*)d_in[15];
    const float* bpm  = (const float*)d_in[16];
    const float* Wps  = (const float*)d_in[17];
    const float* bps  = (const float*)d_in[18];
    const float* Wdec = (const float*)d_in[19];
    const float* bdec = (const float*)d_in[20];
    const float* Wdm  = (const float*)d_in[21];
    const float* bdm  = (const float*)d_in[22];
    const float* Wds  = (const float*)d_in[23];
    const float* bds  = (const float*)d_in[24];
    const float* W_ih = (const float*)d_in[25];
    const float* W_hh = (const float*)d_in[26];
    const float* b_ih = (const float*)d_in[27];
    const float* b_hh = (const float*)d_in[28];

    float* out = (float*)d_out_v;

    char* wsb = (char*)d_ws;
    size_t off = 0;
    auto takeB = [&](size_t bytes) {
        char* p = wsb + off; off += (bytes + 255) & ~(size_t)255; return p;
    };
    short* WTpx = (short*)takeB((size_t)1024 * 256 * 2);
    short* WT1  = (short*)takeB((size_t)5120 * 2048 * 2);
    short* WT2  = (short*)takeB((size_t)256 * 1024 * 2);
    short* WTpz = (short*)takeB((size_t)1024 * 128 * 2);
    short* WT4  = (short*)takeB((size_t)4096 * 3072 * 2);
    short* WT56 = (short*)takeB((size_t)768 * 2048 * 2);
    short* xb   = (short*)takeB((size_t)T_DIM * B_DIM * X_DIMC * 2);
    float* hf0  = (float*)takeB((size_t)B_DIM * H_DIMC * 4);
    float* hf1  = (float*)takeB((size_t)B_DIM * H_DIMC * 4);
    short* hb0  = (short*)takeB((size_t)B_DIM * H_DIMC * 2);
    short* hb1  = (short*)takeB((size_t)B_DIM * H_DIMC * 2);
    short* enc_b   = (short*)takeB((size_t)B_DIM * H_DIMC * 2);
    short* prior_b = (short*)takeB((size_t)B_DIM * H_DIMC * 2);
    short* phi_zb  = (short*)takeB((size_t)B_DIM * H_DIMC * 2);
    short* dec_b   = (short*)takeB((size_t)B_DIM * H_DIMC * 2);
    float* ghb_ = (float*)takeB((size_t)B_DIM * 3 * H_DIMC * 4);
    float* gib_ = (float*)takeB((size_t)B_DIM * 3 * H_DIMC * 4);
    float* pmb  = (float*)takeB((size_t)B_DIM * Z_DIMC * 4);
    float* psb  = (float*)takeB((size_t)B_DIM * Z_DIMC * 4);
    unsigned* bar = (unsigned*)takeB((64 * 32 + 64) * 4);
    const size_t phiXb_bytes = (size_t)T_DIM * B_DIM * H_DIMC * 2;
    const bool big = (off + phiXb_bytes) <= ws_size;
    short* phiXb = big ? (short*)takeB(phiXb_bytes) : nullptr;
    short* phiXs = big ? nullptr : (short*)takeB((size_t)B_DIM * H_DIMC * 2);

    const dim3 tb(256), pt(32, 8);

    packT_k<<<dim3(32, 8), pt, 0, stream>>>(Wpx, 1024, WTpx, 256, 0, 0);
    packT_k<<<dim3(32, 64), pt, 0, stream>>>(Wenc, 1024, WT1, 2048, 0, 0);
    packT_k<<<dim3(32, 32), pt, 0, stream>>>(Wpr, 1024, WT1, 2048, 1024, 1024);
    packD_k<<<dim3(3072 * 1024 / 256), tb, 0, stream>>>(W_hh, 1024, WT1, 2048, 2048, 1024, 1024);
    packT_k<<<dim3(4, 32), pt, 0, stream>>>(Wem, 128, WT2, 1024, 0, 0);
    packT_k<<<dim3(4, 32), pt, 0, stream>>>(Wes, 128, WT2, 1024, 128, 0);
    packT_k<<<dim3(32, 4), pt, 0, stream>>>(Wpz, 1024, WTpz, 128, 0, 0);
    packT_k<<<dim3(32, 64), pt, 0, stream>>>(Wdec, 1024, WT4, 3072, 0, 1024);
    packD_k<<<dim3(3072 * 2048 / 256), tb, 0, stream>>>(W_ih, 2048, WT4, 3072, 1024, 0, 2048);
    packT_k<<<dim3(4, 32), pt, 0, stream>>>(Wpm, 128, WT56, 2048, 0, 0);
    packT_k<<<dim3(4, 32), pt, 0, stream>>>(Wps, 128, WT56, 2048, 128, 0);
    packT_k<<<dim3(8, 32), pt, 0, stream>>>(Wdm, 256, WT56, 2048, 256, 1024);
    packT_k<<<dim3(8, 32), pt, 0, stream>>>(Wds, 256, WT56, 2048, 512, 1024);

    cvtx_k<<<dim3((size_t)T_DIM * B_DIM * X_DIMC / 4 / 256), tb, 0, stream>>>(x, xb);
    hinit_k<<<dim3(B_DIM * H_DIMC / 256), tb, 0, stream>>>(h0, hf0, hb0);
    init_k<<<1, 256, 0, stream>>>(bar, out);

    PP p;
    p.xb = xb; p.x = x; p.eps = eps;
    p.WTpx = WTpx; p.WT1 = WT1; p.WT2 = WT2; p.WTpz = WTpz; p.WT4 = WT4; p.WT56 = WT56;
    p.bpx = bpx; p.benc = benc; p.bpr = bpr; p.bhh = b_hh; p.bem = bem; p.bes = bes;
    p.bpz = bpz; p.bdec = bdec; p.bih = b_ih; p.bpm = bpm; p.bps = bps;
    p.bdm = bdm; p.bds = bds;
    p.hf0 = hf0; p.hf1 = hf1; p.hb0 = hb0; p.hb1 = hb1;
    p.enc_b = enc_b; p.prior_b = prior_b; p.phi_zb = phi_zb; p.dec_b = dec_b;
    p.phiXb = phiXb; p.phiXs = phiXs;
    p.ghb = ghb_; p.gib = gib_; p.pmb = pmb; p.psb = psb;
    p.kld = out; p.em = out + 2;
    p.es = p.em + (size_t)T_DIM * B_DIM * Z_DIMC;
    p.dm = p.es + (size_t)T_DIM * B_DIM * Z_DIMC;
    p.ds = p.dm + (size_t)T_DIM * B_DIM * X_DIMC;
    p.bar = bar; p.big = big ? 1 : 0;

    vrnn_k<<<dim3(NBLK), tb, 0, stream>>>(p);
}

// Round 10
// 15542.882 us; speedup vs baseline: 1.4164x; 1.4164x over previous
//
#include <hip/hip_runtime.h>
#include <math.h>
#include <limits.h>

#define T_DIM 128
#define B_DIM 256
#define X_DIMC 256
#define H_DIMC 1024
#define Z_DIMC 128
#define EPSF 1.1920929e-07f
#define HALF_LOG_2PI 0.91893853320467274f
#define NBLK 768
#define NPB (NBLK / 64)
#define BARN ((66 + 64) * 32)

typedef float f32x4 __attribute__((ext_vector_type(4)));
typedef short bf16x8 __attribute__((ext_vector_type(8)));

// column segment: [prev n_end, n_end) uses K-range [kbeg,kend) of the virtual A
struct Seg { int n_end; int kbeg; int kend; const float* bias; int act;
             float* of32; int ld32; short* ob16; int ld16; };
struct Segs { Seg s[4]; };

__host__ __device__ static inline Seg dseg(int n_end, int kbeg, int kend,
    const float* bias, int act, float* of32, int ld32, short* ob16, int ld16)
{
    Seg s; s.n_end = n_end; s.kbeg = kbeg; s.kend = kend; s.bias = bias;
    s.act = act; s.of32 = of32; s.ld32 = ld32; s.ob16 = ob16; s.ld16 = ld16;
    return s;
}
__host__ __device__ static inline Seg dsegend()
{ return dseg(INT_MAX, 0, 64, nullptr, 0, nullptr, 0, nullptr, 0); }

__device__ __forceinline__ short f2bf(float f) {
    unsigned u = __builtin_bit_cast(unsigned, f);
    u += 0x7fffu + ((u >> 16) & 1u);
    return (short)(u >> 16);
}
__device__ __forceinline__ float act_apply(float x, int act) {
    if (act == 1) return fmaxf(x, 0.f);
    if (act == 2) return x > 0.f ? x + log1pf(expf(-x)) : log1pf(expf(x));
    return x;
}
// weights: normal cached load (read-only during kernel -> never stale)
__device__ __forceinline__ void gload16(const short* g, short* l) {
    __builtin_amdgcn_global_load_lds(
        (const __attribute__((address_space(1))) void*)g,
        (__attribute__((address_space(3))) void*)l, 16, 0, 0);
}
// activations: sc0|sc1 -> coherent at L3 (proven r6)
__device__ __forceinline__ void gload16a(const short* g, short* l) {
    __builtin_amdgcn_global_load_lds(
        (const __attribute__((address_space(1))) void*)g,
        (__attribute__((address_space(3))) void*)l, 16, 0, 17);
}
__device__ __forceinline__ float ldf(const float* p) {
    return __hip_atomic_load(p, __ATOMIC_RELAXED, __HIP_MEMORY_SCOPE_AGENT);
}
__device__ __forceinline__ void stf(float* p, float v) {
    __hip_atomic_store(p, v, __ATOMIC_RELAXED, __HIP_MEMORY_SCOPE_AGENT);
}
__device__ __forceinline__ void sth(short* p, short v) {
    __hip_atomic_store(p, v, __ATOMIC_RELAXED, __HIP_MEMORY_SCOPE_AGENT);
}

// ---- fence-free TWO-LEVEL tree grid barrier ----
// Monotonic counters, no resets. Arrivals: leaf RMW; every NPB-th bumps root;
// 64th root arrival publishes root_gen = phase. Dissemination: each leaf's
// last-arriver polls root_gen (64 pollers on 1 line) and republishes to its
// leaf_gen line; remaining blocks poll their leaf_gen (<=11 pollers/line).
// Constant-immediate two-stage sleep backoff (s_sleep needs a literal).
// Causality: a phase-q publisher exists only after phase-p publication was
// observed by all its leaf's blocks, so leaf_gen never regresses.
__device__ __forceinline__ void gridbar(unsigned* bar, int phase) {
    __syncthreads();
    if (threadIdx.x == 0) {
        asm volatile("s_waitcnt vmcnt(0) lgkmcnt(0)" ::: "memory");
        const int leaf = blockIdx.x & 63;
        unsigned* leafc = bar + (leaf << 5);
        unsigned* rootc = bar + (64 << 5);
        unsigned* rgen  = bar + (65 << 5);
        unsigned* lgen  = bar + ((66 + leaf) << 5);
        unsigned old = __hip_atomic_fetch_add(leafc, 1u, __ATOMIC_RELAXED,
                                              __HIP_MEMORY_SCOPE_AGENT);
        if (((old + 1u) % (unsigned)NPB) == 0u) {
            unsigned r = __hip_atomic_fetch_add(rootc, 1u, __ATOMIC_RELAXED,
                                                __HIP_MEMORY_SCOPE_AGENT);
            if (((r + 1u) & 63u) == 0u)
                __hip_atomic_store(rgen, (r + 1u) >> 6, __ATOMIC_RELAXED,
                                   __HIP_MEMORY_SCOPE_AGENT);
            unsigned g; int it = 0;
            while ((int)(g = __hip_atomic_load(rgen, __ATOMIC_RELAXED,
                                               __HIP_MEMORY_SCOPE_AGENT)) < phase) {
                if (it < 4) { __builtin_amdgcn_s_sleep(1); ++it; }
                else        { __builtin_amdgcn_s_sleep(8); }
            }
            __hip_atomic_store(lgen, g, __ATOMIC_RELAXED,
                               __HIP_MEMORY_SCOPE_AGENT);
        } else {
            int it = 0;
            while ((int)__hip_atomic_load(lgen, __ATOMIC_RELAXED,
                                          __HIP_MEMORY_SCOPE_AGENT) < phase) {
                if (it < 4) { __builtin_amdgcn_s_sleep(1); ++it; }
                else        { __builtin_amdgcn_s_sleep(8); }
            }
        }
    }
    __syncthreads();
}

// ---- 64x64 GEMM tile (r6-proven): depth-3 prefetch, counted vmcnt, swizzle --
__device__ __forceinline__ void gemm_tile(
    short* __restrict__ smem, int bm0, int bn0,
    const short* __restrict__ A0, int lda0,
    const short* __restrict__ A1, int lda1,
    const short* __restrict__ A2, int lda2,
    int ks1, int ks2,
    const short* __restrict__ BT, int ldb, const Segs& segs)
{
    short* As = smem;            // [3][64][64] flat
    short* Bs = smem + 12288;
    const int tid = threadIdx.x, lane = tid & 63, wid = tid >> 6;
    __syncthreads();             // previous unit's LDS reads complete
    Seg sg; int n0;
    if      (bn0 < segs.s[0].n_end) { sg = segs.s[0]; n0 = 0; }
    else if (bn0 < segs.s[1].n_end) { sg = segs.s[1]; n0 = segs.s[0].n_end; }
    else if (bn0 < segs.s[2].n_end) { sg = segs.s[2]; n0 = segs.s[1].n_end; }
    else                            { sg = segs.s[3]; n0 = segs.s[2].n_end; }
    const int nit = (sg.kend - sg.kbeg) >> 6;
    const int row8 = lane >> 3;
    const int kc = ((lane & 7) ^ row8) << 3;   // pre-swizzled source col
    const int r0 = (wid << 4) + row8, r1 = r0 + 8;

    auto srcA = [&](int r, int gk) -> const short* {
        return (gk < ks1) ? A0 + (size_t)(bm0 + r) * lda0 + gk
             : (gk < ks2) ? A1 + (size_t)(bm0 + r) * lda1 + (gk - ks1)
                          : A2 + (size_t)(bm0 + r) * lda2 + (gk - ks2);
    };
    auto stage = [&](int p, int it) {
        const int gk = sg.kbeg + (it << 6) + kc;
        gload16a(srcA(r0, gk), As + p * 4096 + ((wid << 4) + 0) * 64);
        gload16a(srcA(r1, gk), As + p * 4096 + ((wid << 4) + 8) * 64);
        gload16(BT + (size_t)(bn0 + r0) * ldb + gk, Bs + p * 4096 + ((wid << 4) + 0) * 64);
        gload16(BT + (size_t)(bn0 + r1) * ldb + gk, Bs + p * 4096 + ((wid << 4) + 8) * 64);
    };

    const int l15 = lane & 15, lg = lane >> 4;
    const int wm = (wid >> 1) << 5, wn = (wid & 1) << 5;
    const int swz = (l15 & 7) << 3;
    const int c0 = (lg << 3) ^ swz;
    const int c1 = (32 + (lg << 3)) ^ swz;
    f32x4 acc[2][2] = {};

    stage(0, 0);
    if (nit > 1) stage(1, 1);
    if (nit > 2) stage(2, 2);
    int p = 0;
    for (int it = 0; it < nit; ++it) {
        const int rem = nit - 1 - it;
        if (rem >= 2)      asm volatile("s_waitcnt vmcnt(8)" ::: "memory");
        else if (rem == 1) asm volatile("s_waitcnt vmcnt(4)" ::: "memory");
        else               asm volatile("s_waitcnt vmcnt(0)" ::: "memory");
        asm volatile("s_barrier" ::: "memory");
        const short* Ap = As + p * 4096;
        const short* Bp = Bs + p * 4096;
        bf16x8 a00 = *(const bf16x8*)(Ap + (wm + l15) * 64 + c0);
        bf16x8 a01 = *(const bf16x8*)(Ap + (wm + l15) * 64 + c1);
        bf16x8 a10 = *(const bf16x8*)(Ap + (wm + 16 + l15) * 64 + c0);
        bf16x8 a11 = *(const bf16x8*)(Ap + (wm + 16 + l15) * 64 + c1);
        bf16x8 b00 = *(const bf16x8*)(Bp + (wn + l15) * 64 + c0);
        bf16x8 b01 = *(const bf16x8*)(Bp + (wn + l15) * 64 + c1);
        bf16x8 b10 = *(const bf16x8*)(Bp + (wn + 16 + l15) * 64 + c0);
        bf16x8 b11 = *(const bf16x8*)(Bp + (wn + 16 + l15) * 64 + c1);
        acc[0][0] = __builtin_amdgcn_mfma_f32_16x16x32_bf16(a00, b00, acc[0][0], 0, 0, 0);
        acc[0][1] = __builtin_amdgcn_mfma_f32_16x16x32_bf16(a00, b10, acc[0][1], 0, 0, 0);
        acc[1][0] = __builtin_amdgcn_mfma_f32_16x16x32_bf16(a10, b00, acc[1][0], 0, 0, 0);
        acc[1][1] = __builtin_amdgcn_mfma_f32_16x16x32_bf16(a10, b10, acc[1][1], 0, 0, 0);
        acc[0][0] = __builtin_amdgcn_mfma_f32_16x16x32_bf16(a01, b01, acc[0][0], 0, 0, 0);
        acc[0][1] = __builtin_amdgcn_mfma_f32_16x16x32_bf16(a01, b11, acc[0][1], 0, 0, 0);
        acc[1][0] = __builtin_amdgcn_mfma_f32_16x16x32_bf16(a11, b01, acc[1][0], 0, 0, 0);
        acc[1][1] = __builtin_amdgcn_mfma_f32_16x16x32_bf16(a11, b11, acc[1][1], 0, 0, 0);
        if (rem >= 3) {
            asm volatile("s_waitcnt lgkmcnt(0)\n\ts_barrier" ::: "memory");
            stage(p, it + 3);
        }
        p = (p == 2) ? 0 : p + 1;
    }

    // C/D mapping: col = lane&15, row = (lane>>4)*4 + r
#pragma unroll
    for (int j = 0; j < 2; ++j) {
        const int gn = bn0 + wn + (j << 4) + l15;
        const int cn = gn - n0;
        const float bv = sg.bias[cn];
#pragma unroll
        for (int i = 0; i < 2; ++i) {
            const int gm0 = bm0 + wm + (i << 4) + (lg << 2);
#pragma unroll
            for (int r = 0; r < 4; ++r) {
                float v = act_apply(acc[i][j][r] + bv, sg.act);
                if (sg.of32) stf(sg.of32 + (size_t)(gm0 + r) * sg.ld32 + cn, v);
                if (sg.ob16) sth(sg.ob16 + (size_t)(gm0 + r) * sg.ld16 + cn, f2bf(v));
            }
        }
    }
}

// ---- z-GEMM tile: A = em + eps*es on the fly (sc1 reads), K=128 one-shot ----
__device__ __forceinline__ void z_tile(
    short* __restrict__ smem, int bm0, int bn0,
    const float* __restrict__ zm, const float* __restrict__ zs,
    const float* __restrict__ ze,
    const short* __restrict__ BT, const float* __restrict__ bias,
    short* __restrict__ outb)
{
    short* Az = smem;            // [64][136]
    short* Bz = smem + 64 * 136;
    const int tid = threadIdx.x, lane = tid & 63, wid = tid >> 6;
    __syncthreads();
    const int r = tid >> 2, c0i = (tid & 3) << 3;
#pragma unroll
    for (int s = 0; s < 4; ++s) {
        const int col = c0i + s * 32;
        const size_t base = (size_t)(bm0 + r) * 128 + col;
        short tmp[8];
#pragma unroll
        for (int q = 0; q < 8; ++q) {
            const float m = ldf(zm + base + q);
            const float sd = ldf(zs + base + q);
            const float e = ze[base + q];     // input, read-only: cached
            tmp[q] = f2bf(fmaf(e, sd, m));
        }
        *(bf16x8*)(Az + r * 136 + col) = *(bf16x8*)tmp;
        *(bf16x8*)(Bz + r * 136 + col) =
            *(const bf16x8*)(BT + (size_t)(bn0 + r) * 128 + col);
    }
    __syncthreads();
    const int l15 = lane & 15, lg = lane >> 4;
    const int wm = (wid >> 1) << 5, wn = (wid & 1) << 5;
    f32x4 acc[2][2] = {};
#pragma unroll
    for (int s = 0; s < 4; ++s) {
        bf16x8 af0 = *(const bf16x8*)(Az + (wm + l15) * 136 + (lg << 3) + s * 32);
        bf16x8 af1 = *(const bf16x8*)(Az + (wm + 16 + l15) * 136 + (lg << 3) + s * 32);
        bf16x8 bg0 = *(const bf16x8*)(Bz + (wn + l15) * 136 + (lg << 3) + s * 32);
        bf16x8 bg1 = *(const bf16x8*)(Bz + (wn + 16 + l15) * 136 + (lg << 3) + s * 32);
        acc[0][0] = __builtin_amdgcn_mfma_f32_16x16x32_bf16(af0, bg0, acc[0][0], 0, 0, 0);
        acc[0][1] = __builtin_amdgcn_mfma_f32_16x16x32_bf16(af0, bg1, acc[0][1], 0, 0, 0);
        acc[1][0] = __builtin_amdgcn_mfma_f32_16x16x32_bf16(af1, bg0, acc[1][0], 0, 0, 0);
        acc[1][1] = __builtin_amdgcn_mfma_f32_16x16x32_bf16(af1, bg1, acc[1][1], 0, 0, 0);
    }
#pragma unroll
    for (int j = 0; j < 2; ++j) {
        const int gn = bn0 + wn + (j << 4) + l15;
        const float bv = bias[gn];
#pragma unroll
        for (int i = 0; i < 2; ++i) {
            const int gm0 = bm0 + wm + (i << 4) + (lg << 2);
#pragma unroll
            for (int rr = 0; rr < 4; ++rr) {
                float v = fmaxf(acc[i][j][rr] + bv, 0.f);
                sth(outb + (size_t)(gm0 + rr) * 1024 + gn, f2bf(v));
            }
        }
    }
}

__device__ __forceinline__ void gru_unit(int uid, int tid,
    const float* __restrict__ gi, const float* __restrict__ gh,
    const float* __restrict__ h, float* __restrict__ hn, short* __restrict__ hnb)
{
    const int i = uid * 256 + tid;
    const int b = i >> 10, j = i & (H_DIMC - 1);
    const float* gib = gi + (size_t)b * 3 * H_DIMC;
    const float* ghb = gh + (size_t)b * 3 * H_DIMC;
    const float r = 1.f / (1.f + expf(-(ldf(gib + j) + ldf(ghb + j))));
    const float u = 1.f / (1.f + expf(-(ldf(gib + H_DIMC + j) + ldf(ghb + H_DIMC + j))));
    const float n = tanhf(ldf(gib + 2 * H_DIMC + j) + r * ldf(ghb + 2 * H_DIMC + j));
    const float v = (1.f - u) * n + u * ldf(h + i);
    stf(hn + i, v); sth(hnb + i, f2bf(v));
}

// uid in [0,384): [0,128) kld over B*Z, [128,384) nll over B*X
__device__ __forceinline__ void loss_unit(int uid, int tid,
    const float* __restrict__ em, const float* __restrict__ es,
    const float* __restrict__ pm, const float* __restrict__ ps,
    const float* __restrict__ xt, const float* __restrict__ dm,
    const float* __restrict__ ds, float* __restrict__ outp, float* sred)
{
    const int KB = (B_DIM * Z_DIMC) / 256;  // 128
    float v; int target;
    if (uid < KB) {
        const int i = uid * 256 + tid;
        const float esv = ldf(es + i), psv = ldf(ps + i);
        const float dmn = ldf(em + i) - ldf(pm + i);
        v = 0.5f * (2.f * logf(psv + EPSF) - 2.f * logf(esv + EPSF) +
                    (esv * esv + dmn * dmn) / (psv * psv) - 1.f);
        target = 0;
    } else {
        const int i = (uid - KB) * 256 + tid;
        const float d = ldf(ds + i);
        const float diff = xt[i] - ldf(dm + i);
        v = logf(d + EPSF) + HALF_LOG_2PI + diff * diff / (2.f * d * d);
        target = 1;
    }
    for (int o = 32; o > 0; o >>= 1) v += __shfl_down(v, o);
    if ((tid & 63) == 0) sred[tid >> 6] = v;
    __syncthreads();
    if (tid == 0) atomicAdd(outp + target, sred[0] + sred[1] + sred[2] + sred[3]);
    __syncthreads();
}

struct PP {
    const short* xb; const float* x; const float* eps;
    const short *WTpx, *WT1, *WT2, *WTpz, *WT4, *WT56;
    const float *bpx, *benc, *bpr, *bhh, *bem, *bes, *bpz, *bdec, *bih,
                *bpm, *bps, *bdm, *bds;
    float *hf0, *hf1; short *hb0, *hb1;
    short *enc_b, *prior_b, *phi_zb, *dec_b;
    short *phiXb, *phiXs;
    float *ghb, *gib, *pmb, *psb;
    float *kld, *em, *es, *dm, *ds;
    unsigned* bar; int big;
};

// One persistent kernel: whole T-loop, 5 grid-barriered stages per step.
__global__ __launch_bounds__(256, 3) void vrnn_k(PP p)
{
    __shared__ short smem[24576];   // 48KB: GEMM dbuf / zmm carve
    __shared__ float sred[4];
    const int G = gridDim.x, bid = blockIdx.x, tid = threadIdx.x;
    const int BIGK = 1 << 30;
    int ph = 0;

    Segs sx;
    sx.s[0] = dseg(1024, 0, 256, p.bpx, 1, nullptr, 0, p.big ? p.phiXb : p.phiXs, 1024);
    sx.s[1] = dsegend(); sx.s[2] = dsegend(); sx.s[3] = dsegend();

    if (p.big) {  // stage 0: phi_x for all T
        for (int u = bid; u < 512 * 16; u += G)
            gemm_tile(smem, (u & 511) << 6, (u >> 9) << 6,
                      p.xb, 256, p.xb, 256, p.xb, 256, BIGK, BIGK,
                      p.WTpx, 256, sx);
        gridbar(p.bar, ++ph);
    }

    for (int t = 0; t < T_DIM; ++t) {
        float* hcur = (t & 1) ? p.hf1 : p.hf0;
        float* hnxt = (t & 1) ? p.hf0 : p.hf1;
        const short* hbc = (t & 1) ? p.hb1 : p.hb0;
        short* hbn = (t & 1) ? p.hb0 : p.hb1;
        const short* phiXt = p.big ? p.phiXb + (size_t)t * B_DIM * H_DIMC : p.phiXs;
        float* em_t = p.em + (size_t)t * B_DIM * Z_DIMC;
        float* es_t = p.es + (size_t)t * B_DIM * Z_DIMC;
        float* dm_t = p.dm + (size_t)t * B_DIM * X_DIMC;
        float* ds_t = p.ds + (size_t)t * B_DIM * X_DIMC;
        const float* eps_t = p.eps + (size_t)t * B_DIM * Z_DIMC;

        if (!p.big) {
            for (int u = bid; u < 64; u += G)
                gemm_tile(smem, (u & 3) << 6, (u >> 2) << 6,
                          p.xb + (size_t)t * B_DIM * X_DIMC, 256,
                          p.xb, 256, p.xb, 256, BIGK, BIGK, p.WTpx, 256, sx);
            gridbar(p.bar, ++ph);
        }
        // Stage A: G1 [phiX|h] -> enc | prior | gh ; + loss(t-1)
        {
            Segs g1;
            g1.s[0] = dseg(1024, 0, 2048, p.benc, 1, nullptr, 0, p.enc_b, 1024);
            g1.s[1] = dseg(2048, 1024, 2048, p.bpr, 1, nullptr, 0, p.prior_b, 1024);
            g1.s[2] = dseg(5120, 1024, 2048, p.bhh, 0, p.ghb, 3 * H_DIMC, nullptr, 0);
            g1.s[3] = dsegend();
            const int tp = t - 1;
            const int nA = 320 + (t > 0 ? 384 : 0);
            for (int u = bid; u < nA; u += G) {
                if (u < 320)
                    gemm_tile(smem, (u & 3) << 6, (u >> 2) << 6,
                              phiXt, 1024, hbc, 1024, hbc, 1024, 1024, BIGK,
                              p.WT1, 2048, g1);
                else
                    loss_unit(u - 320, tid,
                              p.em + (size_t)tp * B_DIM * Z_DIMC,
                              p.es + (size_t)tp * B_DIM * Z_DIMC,
                              p.pmb, p.psb,
                              p.x + (size_t)tp * B_DIM * X_DIMC,
                              p.dm + (size_t)tp * B_DIM * X_DIMC,
                              p.ds + (size_t)tp * B_DIM * X_DIMC,
                              p.kld, sred);
            }
            gridbar(p.bar, ++ph);
        }
        // Stage B: G2 enc -> em | es(softplus) (direct to d_out)
        {
            Segs g2;
            g2.s[0] = dseg(128, 0, 1024, p.bem, 0, em_t, 128, nullptr, 0);
            g2.s[1] = dseg(256, 0, 1024, p.bes, 2, es_t, 128, nullptr, 0);
            g2.s[2] = dsegend(); g2.s[3] = dsegend();
            for (int u = bid; u < 16; u += G)
                gemm_tile(smem, (u & 3) << 6, (u >> 2) << 6,
                          p.enc_b, 1024, p.enc_b, 1024, p.enc_b, 1024, BIGK, BIGK,
                          p.WT2, 1024, g2);
            gridbar(p.bar, ++ph);
        }
        // Stage C: z = em + eps*es -> phi_z(relu)
        for (int u = bid; u < 64; u += G)
            z_tile(smem, (u & 3) << 6, (u >> 2) << 6,
                   em_t, es_t, eps_t, p.WTpz, p.bpz, p.phi_zb);
        gridbar(p.bar, ++ph);
        // Stage D: G4 [phiX|phi_z|h] -> dec | gi
        {
            Segs g4;
            g4.s[0] = dseg(1024, 1024, 3072, p.bdec, 1, nullptr, 0, p.dec_b, 1024);
            g4.s[1] = dseg(4096, 0, 2048, p.bih, 0, p.gib, 3 * H_DIMC, nullptr, 0);
            g4.s[2] = dsegend(); g4.s[3] = dsegend();
            for (int u = bid; u < 256; u += G)
                gemm_tile(smem, (u & 3) << 6, (u >> 2) << 6,
                          phiXt, 1024, p.phi_zb, 1024, hbc, 1024, 1024, 2048,
                          p.WT4, 3072, g4);
            gridbar(p.bar, ++ph);
        }
        // Stage E: G56 [prior|dec] -> pm|ps|dm|ds ; + GRU combine
        {
            Segs g5;
            g5.s[0] = dseg(128, 0, 1024, p.bpm, 0, p.pmb, 128, nullptr, 0);
            g5.s[1] = dseg(256, 0, 1024, p.bps, 2, p.psb, 128, nullptr, 0);
            g5.s[2] = dseg(512, 1024, 2048, p.bdm, 0, dm_t, 256, nullptr, 0);
            g5.s[3] = dseg(768, 1024, 2048, p.bds, 2, ds_t, 256, nullptr, 0);
            for (int u = bid; u < 48 + 1024; u += G) {
                if (u < 48)
                    gemm_tile(smem, (u & 3) << 6, (u >> 2) << 6,
                              p.prior_b, 1024, p.dec_b, 1024, p.dec_b, 1024,
                              1024, BIGK, p.WT56, 2048, g5);
                else
                    gru_unit(u - 48, tid, p.gib, p.ghb, hcur, hnxt, hbn);
            }
            gridbar(p.bar, ++ph);
        }
    }
    // final loss for t = T-1
    {
        const int tp = T_DIM - 1;
        for (int u = bid; u < 384; u += G)
            loss_unit(u, tid,
                      p.em + (size_t)tp * B_DIM * Z_DIMC,
                      p.es + (size_t)tp * B_DIM * Z_DIMC,
                      p.pmb, p.psb,
                      p.x + (size_t)tp * B_DIM * X_DIMC,
                      p.dm + (size_t)tp * B_DIM * X_DIMC,
                      p.ds + (size_t)tp * B_DIM * X_DIMC,
                      p.kld, sred);
    }
}

// ---- prologue kernels ----
__global__ void packT_k(const float* __restrict__ src, int ldsr,
                        short* __restrict__ dst, int ldd, int n0, int k0)
{
    __shared__ float tile[32][33];
    const int bx = blockIdx.x * 32, by = blockIdx.y * 32;
    const int tx = threadIdx.x, ty = threadIdx.y;  // (32,8)
    for (int i = ty; i < 32; i += 8)
        tile[i][tx] = src[(size_t)(by + i) * ldsr + bx + tx];
    __syncthreads();
    for (int i = ty; i < 32; i += 8)
        dst[(size_t)(n0 + bx + i) * ldd + k0 + by + tx] = f2bf(tile[tx][i]);
}

__global__ void packD_k(const float* __restrict__ src, int ldsr,
                        short* __restrict__ dst, int ldd, int n0, int k0, int kr)
{
    const int idx = blockIdx.x * 256 + threadIdx.x;
    const int n = idx / kr, k = idx % kr;
    dst[(size_t)(n0 + n) * ldd + k0 + k] = f2bf(src[(size_t)n * ldsr + k]);
}

__global__ void cvtx_k(const float* __restrict__ x, short* __restrict__ xb)
{
    const int i = blockIdx.x * 256 + threadIdx.x;
    float4 v = ((const float4*)x)[i];
    short4 s;
    s.x = f2bf(v.x); s.y = f2bf(v.y); s.z = f2bf(v.z); s.w = f2bf(v.w);
    ((short4*)xb)[i] = s;
}

__global__ void hinit_k(const float* __restrict__ h0, float* __restrict__ hf,
                        short* __restrict__ hb)
{
    const int i = blockIdx.x * 256 + threadIdx.x;
    const float v = h0[i];
    hf[i] = v; hb[i] = f2bf(v);
}

__global__ void init_k(unsigned* bar, float* kn)
{
    for (int i = threadIdx.x; i < BARN; i += 256) bar[i] = 0u;
    if (threadIdx.x < 2) kn[threadIdx.x] = 0.f;
}

extern "C" void kernel_launch(void* const* d_in, const int* in_sizes, int n_in,
                              void* d_out_v, int out_size, void* d_ws, size_t ws_size,
                              hipStream_t stream)
{
    (void)in_sizes; (void)n_in; (void)out_size;
    const float* x    = (const float*)d_in[0];
    const float* h0   = (const float*)d_in[1];
    const float* eps  = (const float*)d_in[2];
    const float* Wpx  = (const float*)d_in[3];
    const float* bpx  = (const float*)d_in[4];
    const float* Wpz  = (const float*)d_in[5];
    const float* bpz  = (const float*)d_in[6];
    const float* Wenc = (const float*)d_in[7];
    const float* benc = (const float*)d_in[8];
    const float* Wem  = (const float*)d_in[9];
    const float* bem  = (const float*)d_in[10];
    const float* Wes  = (const float*)d_in[11];
    const float* bes  = (const float*)d_in[12];
    const float* Wpr  = (const float*)d_in[13];
    const float* bpr  = (const float*)d_in[14];
    const float* Wpm  = (const float*)d_in[15];
    const float* bpm  = (const float*)d_in[16];
    const float* Wps  = (const float*)d_in[17];
    const float* bps  = (const float*)d_in[18];
    const float* Wdec = (const float*)d_in[19];
    const float* bdec = (const float*)d_in[20];
    const float* Wdm  = (const float*)d_in[21];
    const float* bdm  = (const float*)d_in[22];
    const float* Wds  = (const float*)d_in[23];
    const float* bds  = (const float*)d_in[24];
    const float* W_ih = (const float*)d_in[25];
    const float* W_hh = (const float*)d_in[26];
    const float* b_ih = (const float*)d_in[27];
    const float* b_hh = (const float*)d_in[28];

    float* out = (float*)d_out_v;

    char* wsb = (char*)d_ws;
    size_t off = 0;
    auto takeB = [&](size_t bytes) {
        char* p = wsb + off; off += (bytes + 255) & ~(size_t)255; return p;
    };
    short* WTpx = (short*)takeB((size_t)1024 * 256 * 2);
    short* WT1  = (short*)takeB((size_t)5120 * 2048 * 2);
    short* WT2  = (short*)takeB((size_t)256 * 1024 * 2);
    short* WTpz = (short*)takeB((size_t)1024 * 128 * 2);
    short* WT4  = (short*)takeB((size_t)4096 * 3072 * 2);
    short* WT56 = (short*)takeB((size_t)768 * 2048 * 2);
    short* xb   = (short*)takeB((size_t)T_DIM * B_DIM * X_DIMC * 2);
    float* hf0  = (float*)takeB((size_t)B_DIM * H_DIMC * 4);
    float* hf1  = (float*)takeB((size_t)B_DIM * H_DIMC * 4);
    short* hb0  = (short*)takeB((size_t)B_DIM * H_DIMC * 2);
    short* hb1  = (short*)takeB((size_t)B_DIM * H_DIMC * 2);
    short* enc_b   = (short*)takeB((size_t)B_DIM * H_DIMC * 2);
    short* prior_b = (short*)takeB((size_t)B_DIM * H_DIMC * 2);
    short* phi_zb  = (short*)takeB((size_t)B_DIM * H_DIMC * 2);
    short* dec_b   = (short*)takeB((size_t)B_DIM * H_DIMC * 2);
    float* ghb_ = (float*)takeB((size_t)B_DIM * 3 * H_DIMC * 4);
    float* gib_ = (float*)takeB((size_t)B_DIM * 3 * H_DIMC * 4);
    float* pmb  = (float*)takeB((size_t)B_DIM * Z_DIMC * 4);
    float* psb  = (float*)takeB((size_t)B_DIM * Z_DIMC * 4);
    unsigned* bar = (unsigned*)takeB((size_t)BARN * 4);
    const size_t phiXb_bytes = (size_t)T_DIM * B_DIM * H_DIMC * 2;
    const bool big = (off + phiXb_bytes) <= ws_size;
    short* phiXb = big ? (short*)takeB(phiXb_bytes) : nullptr;
    short* phiXs = big ? nullptr : (short*)takeB((size_t)B_DIM * H_DIMC * 2);

    const dim3 tb(256), pt(32, 8);

    // ---- pack weights to bf16 B^T fused layouts ----
    packT_k<<<dim3(32, 8), pt, 0, stream>>>(Wpx, 1024, WTpx, 256, 0, 0);
    packT_k<<<dim3(32, 64), pt, 0, stream>>>(Wenc, 1024, WT1, 2048, 0, 0);
    packT_k<<<dim3(32, 32), pt, 0, stream>>>(Wpr, 1024, WT1, 2048, 1024, 1024);
    packD_k<<<dim3(3072 * 1024 / 256), tb, 0, stream>>>(W_hh, 1024, WT1, 2048, 2048, 1024, 1024);
    packT_k<<<dim3(4, 32), pt, 0, stream>>>(Wem, 128, WT2, 1024, 0, 0);
    packT_k<<<dim3(4, 32), pt, 0, stream>>>(Wes, 128, WT2, 1024, 128, 0);
    packT_k<<<dim3(32, 4), pt, 0, stream>>>(Wpz, 1024, WTpz, 128, 0, 0);
    packT_k<<<dim3(32, 64), pt, 0, stream>>>(Wdec, 1024, WT4, 3072, 0, 1024);
    packD_k<<<dim3(3072 * 2048 / 256), tb, 0, stream>>>(W_ih, 2048, WT4, 3072, 1024, 0, 2048);
    packT_k<<<dim3(4, 32), pt, 0, stream>>>(Wpm, 128, WT56, 2048, 0, 0);
    packT_k<<<dim3(4, 32), pt, 0, stream>>>(Wps, 128, WT56, 2048, 128, 0);
    packT_k<<<dim3(8, 32), pt, 0, stream>>>(Wdm, 256, WT56, 2048, 256, 1024);
    packT_k<<<dim3(8, 32), pt, 0, stream>>>(Wds, 256, WT56, 2048, 512, 1024);

    cvtx_k<<<dim3((size_t)T_DIM * B_DIM * X_DIMC / 4 / 256), tb, 0, stream>>>(x, xb);
    hinit_k<<<dim3(B_DIM * H_DIMC / 256), tb, 0, stream>>>(h0, hf0, hb0);
    init_k<<<1, 256, 0, stream>>>(bar, out);

    PP p;
    p.xb = xb; p.x = x; p.eps = eps;
    p.WTpx = WTpx; p.WT1 = WT1; p.WT2 = WT2; p.WTpz = WTpz; p.WT4 = WT4; p.WT56 = WT56;
    p.bpx = bpx; p.benc = benc; p.bpr = bpr; p.bhh = b_hh; p.bem = bem; p.bes = bes;
    p.bpz = bpz; p.bdec = bdec; p.bih = b_ih; p.bpm = bpm; p.bps = bps;
    p.bdm = bdm; p.bds = bds;
    p.hf0 = hf0; p.hf1 = hf1; p.hb0 = hb0; p.hb1 = hb1;
    p.enc_b = enc_b; p.prior_b = prior_b; p.phi_zb = phi_zb; p.dec_b = dec_b;
    p.phiXb = phiXb; p.phiXs = phiXs;
    p.ghb = ghb_; p.gib = gib_; p.pmb = pmb; p.psb = psb;
    p.kld = out; p.em = out + 2;
    p.es = p.em + (size_t)T_DIM * B_DIM * Z_DIMC;
    p.dm = p.es + (size_t)T_DIM * B_DIM * Z_DIMC;
    p.ds = p.dm + (size_t)T_DIM * B_DIM * X_DIMC;
    p.bar = bar; p.big = big ? 1 : 0;

    vrnn_k<<<dim3(NBLK), tb, 0, stream>>>(p);
}

// Round 11
// 15267.822 us; speedup vs baseline: 1.4419x; 1.0180x over previous
//
#include <hip/hip_runtime.h>
#include <math.h>
#include <limits.h>

#define T_DIM 128
#define B_DIM 256
#define X_DIMC 256
#define H_DIMC 1024
#define Z_DIMC 128
#define EPSF 1.1920929e-07f
#define HALF_LOG_2PI 0.91893853320467274f
#define NBLK 768
#define NPB (NBLK / 64)
#define BARN ((66 + 64) * 32)

typedef float f32x4 __attribute__((ext_vector_type(4)));
typedef short bf16x8 __attribute__((ext_vector_type(8)));

// column segment: [prev n_end, n_end) uses K-range [kbeg,kend) of the virtual A
struct Seg { int n_end; int kbeg; int kend; const float* bias; int act;
             float* of32; int ld32; short* ob16; int ld16; };
struct Segs { Seg s[4]; };

__host__ __device__ static inline Seg dseg(int n_end, int kbeg, int kend,
    const float* bias, int act, float* of32, int ld32, short* ob16, int ld16)
{
    Seg s; s.n_end = n_end; s.kbeg = kbeg; s.kend = kend; s.bias = bias;
    s.act = act; s.of32 = of32; s.ld32 = ld32; s.ob16 = ob16; s.ld16 = ld16;
    return s;
}
__host__ __device__ static inline Seg dsegend()
{ return dseg(INT_MAX, 0, 64, nullptr, 0, nullptr, 0, nullptr, 0); }

__device__ __forceinline__ short f2bf(float f) {
    unsigned u = __builtin_bit_cast(unsigned, f);
    u += 0x7fffu + ((u >> 16) & 1u);
    return (short)(u >> 16);
}
__device__ __forceinline__ float act_apply(float x, int act) {
    if (act == 1) return fmaxf(x, 0.f);
    if (act == 2) return x > 0.f ? x + log1pf(expf(-x)) : log1pf(expf(x));
    return x;
}
// cached load (write-once buffers + weights: never stale within a call;
// deterministic across graph replays -> stale line == current data)
__device__ __forceinline__ void gload16(const short* g, short* l) {
    __builtin_amdgcn_global_load_lds(
        (const __attribute__((address_space(1))) void*)g,
        (__attribute__((address_space(3))) void*)l, 16, 0, 0);
}
// activations mutated within the call: sc0|sc1 -> coherent at L3 (proven r6)
__device__ __forceinline__ void gload16a(const short* g, short* l) {
    __builtin_amdgcn_global_load_lds(
        (const __attribute__((address_space(1))) void*)g,
        (__attribute__((address_space(3))) void*)l, 16, 0, 17);
}
__device__ __forceinline__ float ldf(const float* p) {
    return __hip_atomic_load(p, __ATOMIC_RELAXED, __HIP_MEMORY_SCOPE_AGENT);
}
__device__ __forceinline__ void stf(float* p, float v) {
    __hip_atomic_store(p, v, __ATOMIC_RELAXED, __HIP_MEMORY_SCOPE_AGENT);
}
__device__ __forceinline__ void sth(short* p, short v) {
    __hip_atomic_store(p, v, __ATOMIC_RELAXED, __HIP_MEMORY_SCOPE_AGENT);
}

// ---- fence-free TWO-LEVEL tree grid barrier (r10-proven) ----
__device__ __forceinline__ void gridbar(unsigned* bar, int phase) {
    __syncthreads();
    if (threadIdx.x == 0) {
        asm volatile("s_waitcnt vmcnt(0) lgkmcnt(0)" ::: "memory");
        const int leaf = blockIdx.x & 63;
        unsigned* leafc = bar + (leaf << 5);
        unsigned* rootc = bar + (64 << 5);
        unsigned* rgen  = bar + (65 << 5);
        unsigned* lgen  = bar + ((66 + leaf) << 5);
        unsigned old = __hip_atomic_fetch_add(leafc, 1u, __ATOMIC_RELAXED,
                                              __HIP_MEMORY_SCOPE_AGENT);
        if (((old + 1u) % (unsigned)NPB) == 0u) {
            unsigned r = __hip_atomic_fetch_add(rootc, 1u, __ATOMIC_RELAXED,
                                                __HIP_MEMORY_SCOPE_AGENT);
            if (((r + 1u) & 63u) == 0u)
                __hip_atomic_store(rgen, (r + 1u) >> 6, __ATOMIC_RELAXED,
                                   __HIP_MEMORY_SCOPE_AGENT);
            unsigned g; int it = 0;
            while ((int)(g = __hip_atomic_load(rgen, __ATOMIC_RELAXED,
                                               __HIP_MEMORY_SCOPE_AGENT)) < phase) {
                if (it < 4) { __builtin_amdgcn_s_sleep(1); ++it; }
                else        { __builtin_amdgcn_s_sleep(8); }
            }
            __hip_atomic_store(lgen, g, __ATOMIC_RELAXED,
                               __HIP_MEMORY_SCOPE_AGENT);
        } else {
            int it = 0;
            while ((int)__hip_atomic_load(lgen, __ATOMIC_RELAXED,
                                          __HIP_MEMORY_SCOPE_AGENT) < phase) {
                if (it < 4) { __builtin_amdgcn_s_sleep(1); ++it; }
                else        { __builtin_amdgcn_s_sleep(8); }
            }
        }
    }
    __syncthreads();
}

// ---- 64x64 GEMM tile: BK=32, DEPTH-6 prefetch, counted vmcnt ----
// LDS: As[6][64][32] + Bs[6][64][32] = 48KB. Per iter: 2 loads/wave (1KB A +
// 1KB B chunk), 4 ds_read_b128, 4 MFMA. Rotation-XOR octet swizzle
// (oct ^= (row>>1)&3) gives 2-way (free) LDS reads; applied on the GLOBAL
// source address (linear LDS dest, rule #21) and the read side identically.
// a0c: A0 segment (k<ks1) is a write-once buffer -> cached load path.
__device__ __forceinline__ void gemm_tile(
    short* __restrict__ smem, int bm0, int bn0,
    const short* __restrict__ A0, int lda0,
    const short* __restrict__ A1, int lda1,
    const short* __restrict__ A2, int lda2,
    int ks1, int ks2, int a0c,
    const short* __restrict__ BT, int ldb, const Segs& segs)
{
    short* As = smem;            // [6][64][32] = 12288 shorts
    short* Bs = smem + 12288;
    const int tid = threadIdx.x, lane = tid & 63, wid = tid >> 6;
    __syncthreads();             // previous unit's LDS reads complete
    Seg sg; int n0;
    if      (bn0 < segs.s[0].n_end) { sg = segs.s[0]; n0 = 0; }
    else if (bn0 < segs.s[1].n_end) { sg = segs.s[1]; n0 = segs.s[0].n_end; }
    else if (bn0 < segs.s[2].n_end) { sg = segs.s[2]; n0 = segs.s[1].n_end; }
    else                            { sg = segs.s[3]; n0 = segs.s[2].n_end; }
    const int nit = (sg.kend - sg.kbeg) >> 5;
    // staging: wave w moves rows [16w,16w+16) of A and B as one 1KB chunk each.
    // lane l -> row16 = l>>2, phys oct = l&3; logical (global) oct pre-swizzled.
    const int row16 = lane >> 2;
    const int kc = ((lane & 3) ^ ((lane >> 3) & 3)) << 3;  // swizzled src col
    const int r0 = (wid << 4) + row16;

    auto srcA = [&](int gk) -> const short* {
        return (gk < ks1) ? A0 + (size_t)(bm0 + r0) * lda0 + gk
             : (gk < ks2) ? A1 + (size_t)(bm0 + r0) * lda1 + (gk - ks1)
                          : A2 + (size_t)(bm0 + r0) * lda2 + (gk - ks2);
    };
    auto stage = [&](int p, int it) {
        const int gk = sg.kbeg + (it << 5) + kc;
        short* dA = As + p * 2048 + (wid << 9);
        short* dB = Bs + p * 2048 + (wid << 9);
        const short* ga = srcA(gk);
        if (a0c && gk < ks1) gload16(ga, dA);
        else                 gload16a(ga, dA);
        gload16(BT + (size_t)(bn0 + r0) * ldb + gk, dB);
    };

    const int l15 = lane & 15, lg = lane >> 4;
    const int wm = (wid >> 1) << 5, wn = (wid & 1) << 5;
    const int co = (lg ^ ((l15 >> 1) & 3)) << 3;  // phys oct for row base+l15
    f32x4 acc[2][2] = {};

#pragma unroll
    for (int i = 0; i < 6; ++i) if (i < nit) stage(i, i);
    int p = 0;
    for (int it = 0; it < nit; ++it) {
        const int rem = nit - 1 - it;
        if      (rem >= 5) asm volatile("s_waitcnt vmcnt(10)" ::: "memory");
        else if (rem == 4) asm volatile("s_waitcnt vmcnt(8)" ::: "memory");
        else if (rem == 3) asm volatile("s_waitcnt vmcnt(6)" ::: "memory");
        else if (rem == 2) asm volatile("s_waitcnt vmcnt(4)" ::: "memory");
        else if (rem == 1) asm volatile("s_waitcnt vmcnt(2)" ::: "memory");
        else               asm volatile("s_waitcnt vmcnt(0)" ::: "memory");
        asm volatile("s_barrier" ::: "memory");
        const short* Ap = As + p * 2048;
        const short* Bp = Bs + p * 2048;
        bf16x8 a0 = *(const bf16x8*)(Ap + (wm + l15) * 32 + co);
        bf16x8 a1 = *(const bf16x8*)(Ap + (wm + 16 + l15) * 32 + co);
        bf16x8 b0 = *(const bf16x8*)(Bp + (wn + l15) * 32 + co);
        bf16x8 b1 = *(const bf16x8*)(Bp + (wn + 16 + l15) * 32 + co);
        acc[0][0] = __builtin_amdgcn_mfma_f32_16x16x32_bf16(a0, b0, acc[0][0], 0, 0, 0);
        acc[0][1] = __builtin_amdgcn_mfma_f32_16x16x32_bf16(a0, b1, acc[0][1], 0, 0, 0);
        acc[1][0] = __builtin_amdgcn_mfma_f32_16x16x32_bf16(a1, b0, acc[1][0], 0, 0, 0);
        acc[1][1] = __builtin_amdgcn_mfma_f32_16x16x32_bf16(a1, b1, acc[1][1], 0, 0, 0);
        if (rem >= 6) {
            asm volatile("s_waitcnt lgkmcnt(0)\n\ts_barrier" ::: "memory");
            stage(p, it + 6);
        }
        p = (p == 5) ? 0 : p + 1;
    }

    // C/D mapping: col = lane&15, row = (lane>>4)*4 + r
#pragma unroll
    for (int j = 0; j < 2; ++j) {
        const int gn = bn0 + wn + (j << 4) + l15;
        const int cn = gn - n0;
        const float bv = sg.bias[cn];
#pragma unroll
        for (int i = 0; i < 2; ++i) {
            const int gm0 = bm0 + wm + (i << 4) + (lg << 2);
#pragma unroll
            for (int r = 0; r < 4; ++r) {
                float v = act_apply(acc[i][j][r] + bv, sg.act);
                if (sg.of32) stf(sg.of32 + (size_t)(gm0 + r) * sg.ld32 + cn, v);
                if (sg.ob16) sth(sg.ob16 + (size_t)(gm0 + r) * sg.ld16 + cn, f2bf(v));
            }
        }
    }
}

// ---- z-GEMM tile: A = em + eps*es on the fly (sc1 reads), K=128 one-shot ----
__device__ __forceinline__ void z_tile(
    short* __restrict__ smem, int bm0, int bn0,
    const float* __restrict__ zm, const float* __restrict__ zs,
    const float* __restrict__ ze,
    const short* __restrict__ BT, const float* __restrict__ bias,
    short* __restrict__ outb)
{
    short* Az = smem;            // [64][136]
    short* Bz = smem + 64 * 136;
    const int tid = threadIdx.x, lane = tid & 63, wid = tid >> 6;
    __syncthreads();
    const int r = tid >> 2, c0i = (tid & 3) << 3;
#pragma unroll
    for (int s = 0; s < 4; ++s) {
        const int col = c0i + s * 32;
        const size_t base = (size_t)(bm0 + r) * 128 + col;
        short tmp[8];
#pragma unroll
        for (int q = 0; q < 8; ++q) {
            const float m = ldf(zm + base + q);
            const float sd = ldf(zs + base + q);
            const float e = ze[base + q];     // input, read-only: cached
            tmp[q] = f2bf(fmaf(e, sd, m));
        }
        *(bf16x8*)(Az + r * 136 + col) = *(bf16x8*)tmp;
        *(bf16x8*)(Bz + r * 136 + col) =
            *(const bf16x8*)(BT + (size_t)(bn0 + r) * 128 + col);
    }
    __syncthreads();
    const int l15 = lane & 15, lg = lane >> 4;
    const int wm = (wid >> 1) << 5, wn = (wid & 1) << 5;
    f32x4 acc[2][2] = {};
#pragma unroll
    for (int s = 0; s < 4; ++s) {
        bf16x8 af0 = *(const bf16x8*)(Az + (wm + l15) * 136 + (lg << 3) + s * 32);
        bf16x8 af1 = *(const bf16x8*)(Az + (wm + 16 + l15) * 136 + (lg << 3) + s * 32);
        bf16x8 bg0 = *(const bf16x8*)(Bz + (wn + l15) * 136 + (lg << 3) + s * 32);
        bf16x8 bg1 = *(const bf16x8*)(Bz + (wn + 16 + l15) * 136 + (lg << 3) + s * 32);
        acc[0][0] = __builtin_amdgcn_mfma_f32_16x16x32_bf16(af0, bg0, acc[0][0], 0, 0, 0);
        acc[0][1] = __builtin_amdgcn_mfma_f32_16x16x32_bf16(af0, bg1, acc[0][1], 0, 0, 0);
        acc[1][0] = __builtin_amdgcn_mfma_f32_16x16x32_bf16(af1, bg0, acc[1][0], 0, 0, 0);
        acc[1][1] = __builtin_amdgcn_mfma_f32_16x16x32_bf16(af1, bg1, acc[1][1], 0, 0, 0);
    }
#pragma unroll
    for (int j = 0; j < 2; ++j) {
        const int gn = bn0 + wn + (j << 4) + l15;
        const float bv = bias[gn];
#pragma unroll
        for (int i = 0; i < 2; ++i) {
            const int gm0 = bm0 + wm + (i << 4) + (lg << 2);
#pragma unroll
            for (int rr = 0; rr < 4; ++rr) {
                float v = fmaxf(acc[i][j][rr] + bv, 0.f);
                sth(outb + (size_t)(gm0 + rr) * 1024 + gn, f2bf(v));
            }
        }
    }
}

__device__ __forceinline__ void gru_unit(int uid, int tid,
    const float* __restrict__ gi, const float* __restrict__ gh,
    const float* __restrict__ h, float* __restrict__ hn, short* __restrict__ hnb)
{
    const int i = uid * 256 + tid;
    const int b = i >> 10, j = i & (H_DIMC - 1);
    const float* gib = gi + (size_t)b * 3 * H_DIMC;
    const float* ghb = gh + (size_t)b * 3 * H_DIMC;
    const float r = 1.f / (1.f + expf(-(ldf(gib + j) + ldf(ghb + j))));
    const float u = 1.f / (1.f + expf(-(ldf(gib + H_DIMC + j) + ldf(ghb + H_DIMC + j))));
    const float n = tanhf(ldf(gib + 2 * H_DIMC + j) + r * ldf(ghb + 2 * H_DIMC + j));
    const float v = (1.f - u) * n + u * ldf(h + i);
    stf(hn + i, v); sth(hnb + i, f2bf(v));
}

// uid in [0,384): [0,128) kld over B*Z, [128,384) nll over B*X
__device__ __forceinline__ void loss_unit(int uid, int tid,
    const float* __restrict__ em, const float* __restrict__ es,
    const float* __restrict__ pm, const float* __restrict__ ps,
    const float* __restrict__ xt, const float* __restrict__ dm,
    const float* __restrict__ ds, float* __restrict__ outp, float* sred)
{
    const int KB = (B_DIM * Z_DIMC) / 256;  // 128
    float v; int target;
    if (uid < KB) {
        const int i = uid * 256 + tid;
        const float esv = ldf(es + i), psv = ldf(ps + i);
        const float dmn = ldf(em + i) - ldf(pm + i);
        v = 0.5f * (2.f * logf(psv + EPSF) - 2.f * logf(esv + EPSF) +
                    (esv * esv + dmn * dmn) / (psv * psv) - 1.f);
        target = 0;
    } else {
        const int i = (uid - KB) * 256 + tid;
        const float d = ldf(ds + i);
        const float diff = xt[i] - ldf(dm + i);
        v = logf(d + EPSF) + HALF_LOG_2PI + diff * diff / (2.f * d * d);
        target = 1;
    }
    for (int o = 32; o > 0; o >>= 1) v += __shfl_down(v, o);
    if ((tid & 63) == 0) sred[tid >> 6] = v;
    __syncthreads();
    if (tid == 0) atomicAdd(outp + target, sred[0] + sred[1] + sred[2] + sred[3]);
    __syncthreads();
}

struct PP {
    const short* xb; const float* x; const float* eps;
    const short *WTpx, *WT1, *WT2, *WTpz, *WT4, *WT56;
    const float *bpx, *benc, *bpr, *bhh, *bem, *bes, *bpz, *bdec, *bih,
                *bpm, *bps, *bdm, *bds;
    float *hf0, *hf1; short *hb0, *hb1;
    short *enc_b, *prior_b, *phi_zb, *dec_b;
    short *phiXb, *phiXs;
    float *ghb, *gib, *pmb, *psb;
    float *kld, *em, *es, *dm, *ds;
    unsigned* bar; int big;
};

// One persistent kernel: whole T-loop, 5 grid-barriered stages per step.
__global__ __launch_bounds__(256, 3) void vrnn_k(PP p)
{
    __shared__ short smem[24576];   // 48KB: GEMM 6-deep dbuf / zmm carve
    __shared__ float sred[4];
    const int G = gridDim.x, bid = blockIdx.x, tid = threadIdx.x;
    const int BIGK = 1 << 30;
    int ph = 0;

    Segs sx;
    sx.s[0] = dseg(1024, 0, 256, p.bpx, 1, nullptr, 0, p.big ? p.phiXb : p.phiXs, 1024);
    sx.s[1] = dsegend(); sx.s[2] = dsegend(); sx.s[3] = dsegend();

    if (p.big) {  // stage 0: phi_x for all T (xb is write-once -> cached A0)
        for (int u = bid; u < 512 * 16; u += G)
            gemm_tile(smem, (u & 511) << 6, (u >> 9) << 6,
                      p.xb, 256, p.xb, 256, p.xb, 256, BIGK, BIGK, 1,
                      p.WTpx, 256, sx);
        gridbar(p.bar, ++ph);
    }

    for (int t = 0; t < T_DIM; ++t) {
        float* hcur = (t & 1) ? p.hf1 : p.hf0;
        float* hnxt = (t & 1) ? p.hf0 : p.hf1;
        const short* hbc = (t & 1) ? p.hb1 : p.hb0;
        short* hbn = (t & 1) ? p.hb0 : p.hb1;
        const short* phiXt = p.big ? p.phiXb + (size_t)t * B_DIM * H_DIMC : p.phiXs;
        float* em_t = p.em + (size_t)t * B_DIM * Z_DIMC;
        float* es_t = p.es + (size_t)t * B_DIM * Z_DIMC;
        float* dm_t = p.dm + (size_t)t * B_DIM * X_DIMC;
        float* ds_t = p.ds + (size_t)t * B_DIM * X_DIMC;
        const float* eps_t = p.eps + (size_t)t * B_DIM * Z_DIMC;

        if (!p.big) {
            for (int u = bid; u < 64; u += G)
                gemm_tile(smem, (u & 3) << 6, (u >> 2) << 6,
                          p.xb + (size_t)t * B_DIM * X_DIMC, 256,
                          p.xb, 256, p.xb, 256, BIGK, BIGK, 1, p.WTpx, 256, sx);
            gridbar(p.bar, ++ph);
        }
        // Stage A: G1 [phiX(cached)|h(sc1)] -> enc | prior | gh ; + loss(t-1)
        {
            Segs g1;
            g1.s[0] = dseg(1024, 0, 2048, p.benc, 1, nullptr, 0, p.enc_b, 1024);
            g1.s[1] = dseg(2048, 1024, 2048, p.bpr, 1, nullptr, 0, p.prior_b, 1024);
            g1.s[2] = dseg(5120, 1024, 2048, p.bhh, 0, p.ghb, 3 * H_DIMC, nullptr, 0);
            g1.s[3] = dsegend();
            const int tp = t - 1;
            const int nA = 320 + (t > 0 ? 384 : 0);
            for (int u = bid; u < nA; u += G) {
                if (u < 320)
                    gemm_tile(smem, (u & 3) << 6, (u >> 2) << 6,
                              phiXt, 1024, hbc, 1024, hbc, 1024, 1024, BIGK, 1,
                              p.WT1, 2048, g1);
                else
                    loss_unit(u - 320, tid,
                              p.em + (size_t)tp * B_DIM * Z_DIMC,
                              p.es + (size_t)tp * B_DIM * Z_DIMC,
                              p.pmb, p.psb,
                              p.x + (size_t)tp * B_DIM * X_DIMC,
                              p.dm + (size_t)tp * B_DIM * X_DIMC,
                              p.ds + (size_t)tp * B_DIM * X_DIMC,
                              p.kld, sred);
            }
            gridbar(p.bar, ++ph);
        }
        // Stage B: G2 enc -> em | es(softplus) (direct to d_out)
        {
            Segs g2;
            g2.s[0] = dseg(128, 0, 1024, p.bem, 0, em_t, 128, nullptr, 0);
            g2.s[1] = dseg(256, 0, 1024, p.bes, 2, es_t, 128, nullptr, 0);
            g2.s[2] = dsegend(); g2.s[3] = dsegend();
            for (int u = bid; u < 16; u += G)
                gemm_tile(smem, (u & 3) << 6, (u >> 2) << 6,
                          p.enc_b, 1024, p.enc_b, 1024, p.enc_b, 1024, BIGK, BIGK, 0,
                          p.WT2, 1024, g2);
            gridbar(p.bar, ++ph);
        }
        // Stage C: z = em + eps*es -> phi_z(relu)
        for (int u = bid; u < 64; u += G)
            z_tile(smem, (u & 3) << 6, (u >> 2) << 6,
                   em_t, es_t, eps_t, p.WTpz, p.bpz, p.phi_zb);
        gridbar(p.bar, ++ph);
        // Stage D: G4 [phiX(cached)|phi_z|h] -> dec | gi
        {
            Segs g4;
            g4.s[0] = dseg(1024, 1024, 3072, p.bdec, 1, nullptr, 0, p.dec_b, 1024);
            g4.s[1] = dseg(4096, 0, 2048, p.bih, 0, p.gib, 3 * H_DIMC, nullptr, 0);
            g4.s[2] = dsegend(); g4.s[3] = dsegend();
            for (int u = bid; u < 256; u += G)
                gemm_tile(smem, (u & 3) << 6, (u >> 2) << 6,
                          phiXt, 1024, p.phi_zb, 1024, hbc, 1024, 1024, 2048, 1,
                          p.WT4, 3072, g4);
            gridbar(p.bar, ++ph);
        }
        // Stage E: G56 [prior|dec] -> pm|ps|dm|ds ; + GRU combine
        {
            Segs g5;
            g5.s[0] = dseg(128, 0, 1024, p.bpm, 0, p.pmb, 128, nullptr, 0);
            g5.s[1] = dseg(256, 0, 1024, p.bps, 2, p.psb, 128, nullptr, 0);
            g5.s[2] = dseg(512, 1024, 2048, p.bdm, 0, dm_t, 256, nullptr, 0);
            g5.s[3] = dseg(768, 1024, 2048, p.bds, 2, ds_t, 256, nullptr, 0);
            for (int u = bid; u < 48 + 1024; u += G) {
                if (u < 48)
                    gemm_tile(smem, (u & 3) << 6, (u >> 2) << 6,
                              p.prior_b, 1024, p.dec_b, 1024, p.dec_b, 1024,
                              1024, BIGK, 0, p.WT56, 2048, g5);
                else
                    gru_unit(u - 48, tid, p.gib, p.ghb, hcur, hnxt, hbn);
            }
            gridbar(p.bar, ++ph);
        }
    }
    // final loss for t = T-1
    {
        const int tp = T_DIM - 1;
        for (int u = bid; u < 384; u += G)
            loss_unit(u, tid,
                      p.em + (size_t)tp * B_DIM * Z_DIMC,
                      p.es + (size_t)tp * B_DIM * Z_DIMC,
                      p.pmb, p.psb,
                      p.x + (size_t)tp * B_DIM * X_DIMC,
                      p.dm + (size_t)tp * B_DIM * X_DIMC,
                      p.ds + (size_t)tp * B_DIM * X_DIMC,
                      p.kld, sred);
    }
}

// ---- prologue kernels ----
__global__ void packT_k(const float* __restrict__ src, int ldsr,
                        short* __restrict__ dst, int ldd, int n0, int k0)
{
    __shared__ float tile[32][33];
    const int bx = blockIdx.x * 32, by = blockIdx.y * 32;
    const int tx = threadIdx.x, ty = threadIdx.y;  // (32,8)
    for (int i = ty; i < 32; i += 8)
        tile[i][tx] = src[(size_t)(by + i) * ldsr + bx + tx];
    __syncthreads();
    for (int i = ty; i < 32; i += 8)
        dst[(size_t)(n0 + bx + i) * ldd + k0 + by + tx] = f2bf(tile[tx][i]);
}

__global__ void packD_k(const float* __restrict__ src, int ldsr,
                        short* __restrict__ dst, int ldd, int n0, int k0, int kr)
{
    const int idx = blockIdx.x * 256 + threadIdx.x;
    const int n = idx / kr, k = idx % kr;
    dst[(size_t)(n0 + n) * ldd + k0 + k] = f2bf(src[(size_t)n * ldsr + k]);
}

__global__ void cvtx_k(const float* __restrict__ x, short* __restrict__ xb)
{
    const int i = blockIdx.x * 256 + threadIdx.x;
    float4 v = ((const float4*)x)[i];
    short4 s;
    s.x = f2bf(v.x); s.y = f2bf(v.y); s.z = f2bf(v.z); s.w = f2bf(v.w);
    ((short4*)xb)[i] = s;
}

__global__ void hinit_k(const float* __restrict__ h0, float* __restrict__ hf,
                        short* __restrict__ hb)
{
    const int i = blockIdx.x * 256 + threadIdx.x;
    const float v = h0[i];
    hf[i] = v; hb[i] = f2bf(v);
}

__global__ void init_k(unsigned* bar, float* kn)
{
    for (int i = threadIdx.x; i < BARN; i += 256) bar[i] = 0u;
    if (threadIdx.x < 2) kn[threadIdx.x] = 0.f;
}

extern "C" void kernel_launch(void* const* d_in, const int* in_sizes, int n_in,
                              void* d_out_v, int out_size, void* d_ws, size_t ws_size,
                              hipStream_t stream)
{
    (void)in_sizes; (void)n_in; (void)out_size;
    const float* x    = (const float*)d_in[0];
    const float* h0   = (const float*)d_in[1];
    const float* eps  = (const float*)d_in[2];
    const float* Wpx  = (const float*)d_in[3];
    const float* bpx  = (const float*)d_in[4];
    const float* Wpz  = (const float*)d_in[5];
    const float* bpz  = (const float*)d_in[6];
    const float* Wenc = (const float*)d_in[7];
    const float* benc = (const float*)d_in[8];
    const float* Wem  = (const float*)d_in[9];
    const float* bem  = (const float*)d_in[10];
    const float* Wes  = (const float*)d_in[11];
    const float* bes  = (const float*)d_in[12];
    const float* Wpr  = (const float*)d_in[13];
    const float* bpr  = (const float*)d_in[14];
    const float* Wpm  = (const float*)d_in[15];
    const float* bpm  = (const float*)d_in[16];
    const float* Wps  = (const float*)d_in[17];
    const float* bps  = (const float*)d_in[18];
    const float* Wdec = (const float*)d_in[19];
    const float* bdec = (const float*)d_in[20];
    const float* Wdm  = (const float*)d_in[21];
    const float* bdm  = (const float*)d_in[22];
    const float* Wds  = (const float*)d_in[23];
    const float* bds  = (const float*)d_in[24];
    const float* W_ih = (const float*)d_in[25];
    const float* W_hh = (const float*)d_in[26];
    const float* b_ih = (const float*)d_in[27];
    const float* b_hh = (const float*)d_in[28];

    float* out = (float*)d_out_v;

    char* wsb = (char*)d_ws;
    size_t off = 0;
    auto takeB = [&](size_t bytes) {
        char* p = wsb + off; off += (bytes + 255) & ~(size_t)255; return p;
    };
    short* WTpx = (short*)takeB((size_t)1024 * 256 * 2);
    short* WT1  = (short*)takeB((size_t)5120 * 2048 * 2);
    short* WT2  = (short*)takeB((size_t)256 * 1024 * 2);
    short* WTpz = (short*)takeB((size_t)1024 * 128 * 2);
    short* WT4  = (short*)takeB((size_t)4096 * 3072 * 2);
    short* WT56 = (short*)takeB((size_t)768 * 2048 * 2);
    short* xb   = (short*)takeB((size_t)T_DIM * B_DIM * X_DIMC * 2);
    float* hf0  = (float*)takeB((size_t)B_DIM * H_DIMC * 4);
    float* hf1  = (float*)takeB((size_t)B_DIM * H_DIMC * 4);
    short* hb0  = (short*)takeB((size_t)B_DIM * H_DIMC * 2);
    short* hb1  = (short*)takeB((size_t)B_DIM * H_DIMC * 2);
    short* enc_b   = (short*)takeB((size_t)B_DIM * H_DIMC * 2);
    short* prior_b = (short*)takeB((size_t)B_DIM * H_DIMC * 2);
    short* phi_zb  = (short*)takeB((size_t)B_DIM * H_DIMC * 2);
    short* dec_b   = (short*)takeB((size_t)B_DIM * H_DIMC * 2);
    float* ghb_ = (float*)takeB((size_t)B_DIM * 3 * H_DIMC * 4);
    float* gib_ = (float*)takeB((size_t)B_DIM * 3 * H_DIMC * 4);
    float* pmb  = (float*)takeB((size_t)B_DIM * Z_DIMC * 4);
    float* psb  = (float*)takeB((size_t)B_DIM * Z_DIMC * 4);
    unsigned* bar = (unsigned*)takeB((size_t)BARN * 4);
    const size_t phiXb_bytes = (size_t)T_DIM * B_DIM * H_DIMC * 2;
    const bool big = (off + phiXb_bytes) <= ws_size;
    short* phiXb = big ? (short*)takeB(phiXb_bytes) : nullptr;
    short* phiXs = big ? nullptr : (short*)takeB((size_t)B_DIM * H_DIMC * 2);

    const dim3 tb(256), pt(32, 8);

    // ---- pack weights to bf16 B^T fused layouts ----
    packT_k<<<dim3(32, 8), pt, 0, stream>>>(Wpx, 1024, WTpx, 256, 0, 0);
    packT_k<<<dim3(32, 64), pt, 0, stream>>>(Wenc, 1024, WT1, 2048, 0, 0);
    packT_k<<<dim3(32, 32), pt, 0, stream>>>(Wpr, 1024, WT1, 2048, 1024, 1024);
    packD_k<<<dim3(3072 * 1024 / 256), tb, 0, stream>>>(W_hh, 1024, WT1, 2048, 2048, 1024, 1024);
    packT_k<<<dim3(4, 32), pt, 0, stream>>>(Wem, 128, WT2, 1024, 0, 0);
    packT_k<<<dim3(4, 32), pt, 0, stream>>>(Wes, 128, WT2, 1024, 128, 0);
    packT_k<<<dim3(32, 4), pt, 0, stream>>>(Wpz, 1024, WTpz, 128, 0, 0);
    packT_k<<<dim3(32, 64), pt, 0, stream>>>(Wdec, 1024, WT4, 3072, 0, 1024);
    packD_k<<<dim3(3072 * 2048 / 256), tb, 0, stream>>>(W_ih, 2048, WT4, 3072, 1024, 0, 2048);
    packT_k<<<dim3(4, 32), pt, 0, stream>>>(Wpm, 128, WT56, 2048, 0, 0);
    packT_k<<<dim3(4, 32), pt, 0, stream>>>(Wps, 128, WT56, 2048, 128, 0);
    packT_k<<<dim3(8, 32), pt, 0, stream>>>(Wdm, 256, WT56, 2048, 256, 1024);
    packT_k<<<dim3(8, 32), pt, 0, stream>>>(Wds, 256, WT56, 2048, 512, 1024);

    cvtx_k<<<dim3((size_t)T_DIM * B_DIM * X_DIMC / 4 / 256), tb, 0, stream>>>(x, xb);
    hinit_k<<<dim3(B_DIM * H_DIMC / 256), tb, 0, stream>>>(h0, hf0, hb0);
    init_k<<<1, 256, 0, stream>>>(bar, out);

    PP p;
    p.xb = xb; p.x = x; p.eps = eps;
    p.WTpx = WTpx; p.WT1 = WT1; p.WT2 = WT2; p.WTpz = WTpz; p.WT4 = WT4; p.WT56 = WT56;
    p.bpx = bpx; p.benc = benc; p.bpr = bpr; p.bhh = b_hh; p.bem = bem; p.bes = bes;
    p.bpz = bpz; p.bdec = bdec; p.bih = b_ih; p.bpm = bpm; p.bps = bps;
    p.bdm = bdm; p.bds = bds;
    p.hf0 = hf0; p.hf1 = hf1; p.hb0 = hb0; p.hb1 = hb1;
    p.enc_b = enc_b; p.prior_b = prior_b; p.phi_zb = phi_zb; p.dec_b = dec_b;
    p.phiXb = phiXb; p.phiXs = phiXs;
    p.ghb = ghb_; p.gib = gib_; p.pmb = pmb; p.psb = psb;
    p.kld = out; p.em = out + 2;
    p.es = p.em + (size_t)T_DIM * B_DIM * Z_DIMC;
    p.dm = p.es + (size_t)T_DIM * B_DIM * Z_DIMC;
    p.ds = p.dm + (size_t)T_DIM * B_DIM * X_DIMC;
    p.bar = bar; p.big = big ? 1 : 0;

    vrnn_k<<<dim3(NBLK), tb, 0, stream>>>(p);
}

// Round 12
// 14706.694 us; speedup vs baseline: 1.4969x; 1.0382x over previous
//
#include <hip/hip_runtime.h>
#include <math.h>
#include <limits.h>

#define T_DIM 128
#define B_DIM 256
#define X_DIMC 256
#define H_DIMC 1024
#define Z_DIMC 128
#define EPSF 1.1920929e-07f
#define HALF_LOG_2PI 0.91893853320467274f
#define NBLK 768
#define GBLK 384            // blocks per group (2 groups)
#define NPB (GBLK / 64)     // arrivals per leaf per phase
#define BARN ((66 + 64) * 32)

typedef float f32x4 __attribute__((ext_vector_type(4)));
typedef short bf16x8 __attribute__((ext_vector_type(8)));

// column segment: [prev n_end, n_end) uses K-range [kbeg,kend) of the virtual A
struct Seg { int n_end; int kbeg; int kend; const float* bias; int act;
             float* of32; int ld32; short* ob16; int ld16; };
struct Segs { Seg s[4]; };

__host__ __device__ static inline Seg dseg(int n_end, int kbeg, int kend,
    const float* bias, int act, float* of32, int ld32, short* ob16, int ld16)
{
    Seg s; s.n_end = n_end; s.kbeg = kbeg; s.kend = kend; s.bias = bias;
    s.act = act; s.of32 = of32; s.ld32 = ld32; s.ob16 = ob16; s.ld16 = ld16;
    return s;
}
__host__ __device__ static inline Seg dsegend()
{ return dseg(INT_MAX, 0, 64, nullptr, 0, nullptr, 0, nullptr, 0); }

__device__ __forceinline__ short f2bf(float f) {
    unsigned u = __builtin_bit_cast(unsigned, f);
    u += 0x7fffu + ((u >> 16) & 1u);
    return (short)(u >> 16);
}
__device__ __forceinline__ float act_apply(float x, int act) {
    if (act == 1) return fmaxf(x, 0.f);
    if (act == 2) return x > 0.f ? x + log1pf(expf(-x)) : log1pf(expf(x));
    return x;
}
// cached load (weights / write-once buffers)
__device__ __forceinline__ void gload16(const short* g, short* l) {
    __builtin_amdgcn_global_load_lds(
        (const __attribute__((address_space(1))) void*)g,
        (__attribute__((address_space(3))) void*)l, 16, 0, 0);
}
// activations mutated within the call: sc0|sc1 -> coherent at L3 (proven r6)
__device__ __forceinline__ void gload16a(const short* g, short* l) {
    __builtin_amdgcn_global_load_lds(
        (const __attribute__((address_space(1))) void*)g,
        (__attribute__((address_space(3))) void*)l, 16, 0, 17);
}
__device__ __forceinline__ float ldf(const float* p) {
    return __hip_atomic_load(p, __ATOMIC_RELAXED, __HIP_MEMORY_SCOPE_AGENT);
}
__device__ __forceinline__ void stf(float* p, float v) {
    __hip_atomic_store(p, v, __ATOMIC_RELAXED, __HIP_MEMORY_SCOPE_AGENT);
}
__device__ __forceinline__ void sth(short* p, short v) {
    __hip_atomic_store(p, v, __ATOMIC_RELAXED, __HIP_MEMORY_SCOPE_AGENT);
}

// ---- fence-free two-level tree barrier, PER GROUP (r10/r11-proven) ----
// lbid = group-local block id in [0, GBLK). bar = this group's region.
__device__ __forceinline__ void gridbar(unsigned* bar, int phase, int lbid) {
    __syncthreads();
    if (threadIdx.x == 0) {
        asm volatile("s_waitcnt vmcnt(0) lgkmcnt(0)" ::: "memory");
        const int leaf = lbid & 63;
        unsigned* leafc = bar + (leaf << 5);
        unsigned* rootc = bar + (64 << 5);
        unsigned* rgen  = bar + (65 << 5);
        unsigned* lgen  = bar + ((66 + leaf) << 5);
        unsigned old = __hip_atomic_fetch_add(leafc, 1u, __ATOMIC_RELAXED,
                                              __HIP_MEMORY_SCOPE_AGENT);
        if (((old + 1u) % (unsigned)NPB) == 0u) {
            unsigned r = __hip_atomic_fetch_add(rootc, 1u, __ATOMIC_RELAXED,
                                                __HIP_MEMORY_SCOPE_AGENT);
            if (((r + 1u) & 63u) == 0u)
                __hip_atomic_store(rgen, (r + 1u) >> 6, __ATOMIC_RELAXED,
                                   __HIP_MEMORY_SCOPE_AGENT);
            unsigned g; int it = 0;
            while ((int)(g = __hip_atomic_load(rgen, __ATOMIC_RELAXED,
                                               __HIP_MEMORY_SCOPE_AGENT)) < phase) {
                if (it < 4) { __builtin_amdgcn_s_sleep(1); ++it; }
                else        { __builtin_amdgcn_s_sleep(8); }
            }
            __hip_atomic_store(lgen, g, __ATOMIC_RELAXED,
                               __HIP_MEMORY_SCOPE_AGENT);
        } else {
            int it = 0;
            while ((int)__hip_atomic_load(lgen, __ATOMIC_RELAXED,
                                          __HIP_MEMORY_SCOPE_AGENT) < phase) {
                if (it < 4) { __builtin_amdgcn_s_sleep(1); ++it; }
                else        { __builtin_amdgcn_s_sleep(8); }
            }
        }
    }
    __syncthreads();
}

// ---- 64x64 GEMM tile (r11 engine): BK=32, depth-6, counted vmcnt ----
__device__ __forceinline__ void gemm_tile(
    short* __restrict__ smem, int bm0, int bn0,
    const short* __restrict__ A0, int lda0,
    const short* __restrict__ A1, int lda1,
    const short* __restrict__ A2, int lda2,
    int ks1, int ks2, int a0c,
    const short* __restrict__ BT, int ldb, const Segs& segs)
{
    short* As = smem;            // [6][64][32]
    short* Bs = smem + 12288;
    const int tid = threadIdx.x, lane = tid & 63, wid = tid >> 6;
    __syncthreads();
    Seg sg; int n0;
    if      (bn0 < segs.s[0].n_end) { sg = segs.s[0]; n0 = 0; }
    else if (bn0 < segs.s[1].n_end) { sg = segs.s[1]; n0 = segs.s[0].n_end; }
    else if (bn0 < segs.s[2].n_end) { sg = segs.s[2]; n0 = segs.s[1].n_end; }
    else                            { sg = segs.s[3]; n0 = segs.s[2].n_end; }
    const int nit = (sg.kend - sg.kbeg) >> 5;
    const int row16 = lane >> 2;
    const int kc = ((lane & 3) ^ ((lane >> 3) & 3)) << 3;  // swizzled src col
    const int r0 = (wid << 4) + row16;

    auto srcA = [&](int gk) -> const short* {
        return (gk < ks1) ? A0 + (size_t)(bm0 + r0) * lda0 + gk
             : (gk < ks2) ? A1 + (size_t)(bm0 + r0) * lda1 + (gk - ks1)
                          : A2 + (size_t)(bm0 + r0) * lda2 + (gk - ks2);
    };
    auto stage = [&](int p, int it) {
        const int gk = sg.kbeg + (it << 5) + kc;
        short* dA = As + p * 2048 + (wid << 9);
        short* dB = Bs + p * 2048 + (wid << 9);
        const short* ga = srcA(gk);
        if (a0c && gk < ks1) gload16(ga, dA);
        else                 gload16a(ga, dA);
        gload16(BT + (size_t)(bn0 + r0) * ldb + gk, dB);
    };

    const int l15 = lane & 15, lg = lane >> 4;
    const int wm = (wid >> 1) << 5, wn = (wid & 1) << 5;
    const int co = (lg ^ ((l15 >> 1) & 3)) << 3;
    f32x4 acc[2][2] = {};

#pragma unroll
    for (int i = 0; i < 6; ++i) if (i < nit) stage(i, i);
    int p = 0;
    for (int it = 0; it < nit; ++it) {
        const int rem = nit - 1 - it;
        if      (rem >= 5) asm volatile("s_waitcnt vmcnt(10)" ::: "memory");
        else if (rem == 4) asm volatile("s_waitcnt vmcnt(8)" ::: "memory");
        else if (rem == 3) asm volatile("s_waitcnt vmcnt(6)" ::: "memory");
        else if (rem == 2) asm volatile("s_waitcnt vmcnt(4)" ::: "memory");
        else if (rem == 1) asm volatile("s_waitcnt vmcnt(2)" ::: "memory");
        else               asm volatile("s_waitcnt vmcnt(0)" ::: "memory");
        asm volatile("s_barrier" ::: "memory");
        const short* Ap = As + p * 2048;
        const short* Bp = Bs + p * 2048;
        bf16x8 a0 = *(const bf16x8*)(Ap + (wm + l15) * 32 + co);
        bf16x8 a1 = *(const bf16x8*)(Ap + (wm + 16 + l15) * 32 + co);
        bf16x8 b0 = *(const bf16x8*)(Bp + (wn + l15) * 32 + co);
        bf16x8 b1 = *(const bf16x8*)(Bp + (wn + 16 + l15) * 32 + co);
        acc[0][0] = __builtin_amdgcn_mfma_f32_16x16x32_bf16(a0, b0, acc[0][0], 0, 0, 0);
        acc[0][1] = __builtin_amdgcn_mfma_f32_16x16x32_bf16(a0, b1, acc[0][1], 0, 0, 0);
        acc[1][0] = __builtin_amdgcn_mfma_f32_16x16x32_bf16(a1, b0, acc[1][0], 0, 0, 0);
        acc[1][1] = __builtin_amdgcn_mfma_f32_16x16x32_bf16(a1, b1, acc[1][1], 0, 0, 0);
        if (rem >= 6) {
            asm volatile("s_waitcnt lgkmcnt(0)\n\ts_barrier" ::: "memory");
            stage(p, it + 6);
        }
        p = (p == 5) ? 0 : p + 1;
    }

    // C/D mapping: col = lane&15, row = (lane>>4)*4 + r
#pragma unroll
    for (int j = 0; j < 2; ++j) {
        const int gn = bn0 + wn + (j << 4) + l15;
        const int cn = gn - n0;
        const float bv = sg.bias[cn];
#pragma unroll
        for (int i = 0; i < 2; ++i) {
            const int gm0 = bm0 + wm + (i << 4) + (lg << 2);
#pragma unroll
            for (int r = 0; r < 4; ++r) {
                float v = act_apply(acc[i][j][r] + bv, sg.act);
                if (sg.of32) stf(sg.of32 + (size_t)(gm0 + r) * sg.ld32 + cn, v);
                if (sg.ob16) sth(sg.ob16 + (size_t)(gm0 + r) * sg.ld16 + cn, f2bf(v));
            }
        }
    }
}

// ---- z-GEMM tile: A = em + eps*es on the fly (sc1 reads), K=128 one-shot ----
__device__ __forceinline__ void z_tile(
    short* __restrict__ smem, int bm0, int bn0,
    const float* __restrict__ zm, const float* __restrict__ zs,
    const float* __restrict__ ze,
    const short* __restrict__ BT, const float* __restrict__ bias,
    short* __restrict__ outb)
{
    short* Az = smem;            // [64][136]
    short* Bz = smem + 64 * 136;
    const int tid = threadIdx.x, lane = tid & 63, wid = tid >> 6;
    __syncthreads();
    const int r = tid >> 2, c0i = (tid & 3) << 3;
#pragma unroll
    for (int s = 0; s < 4; ++s) {
        const int col = c0i + s * 32;
        const size_t base = (size_t)(bm0 + r) * 128 + col;
        short tmp[8];
#pragma unroll
        for (int q = 0; q < 8; ++q) {
            const float m = ldf(zm + base + q);
            const float sd = ldf(zs + base + q);
            const float e = ze[base + q];
            tmp[q] = f2bf(fmaf(e, sd, m));
        }
        *(bf16x8*)(Az + r * 136 + col) = *(bf16x8*)tmp;
        *(bf16x8*)(Bz + r * 136 + col) =
            *(const bf16x8*)(BT + (size_t)(bn0 + r) * 128 + col);
    }
    __syncthreads();
    const int l15 = lane & 15, lg = lane >> 4;
    const int wm = (wid >> 1) << 5, wn = (wid & 1) << 5;
    f32x4 acc[2][2] = {};
#pragma unroll
    for (int s = 0; s < 4; ++s) {
        bf16x8 af0 = *(const bf16x8*)(Az + (wm + l15) * 136 + (lg << 3) + s * 32);
        bf16x8 af1 = *(const bf16x8*)(Az + (wm + 16 + l15) * 136 + (lg << 3) + s * 32);
        bf16x8 bg0 = *(const bf16x8*)(Bz + (wn + l15) * 136 + (lg << 3) + s * 32);
        bf16x8 bg1 = *(const bf16x8*)(Bz + (wn + 16 + l15) * 136 + (lg << 3) + s * 32);
        acc[0][0] = __builtin_amdgcn_mfma_f32_16x16x32_bf16(af0, bg0, acc[0][0], 0, 0, 0);
        acc[0][1] = __builtin_amdgcn_mfma_f32_16x16x32_bf16(af0, bg1, acc[0][1], 0, 0, 0);
        acc[1][0] = __builtin_amdgcn_mfma_f32_16x16x32_bf16(af1, bg0, acc[1][0], 0, 0, 0);
        acc[1][1] = __builtin_amdgcn_mfma_f32_16x16x32_bf16(af1, bg1, acc[1][1], 0, 0, 0);
    }
#pragma unroll
    for (int j = 0; j < 2; ++j) {
        const int gn = bn0 + wn + (j << 4) + l15;
        const float bv = bias[gn];
#pragma unroll
        for (int i = 0; i < 2; ++i) {
            const int gm0 = bm0 + wm + (i << 4) + (lg << 2);
#pragma unroll
            for (int rr = 0; rr < 4; ++rr) {
                float v = fmaxf(acc[i][j][rr] + bv, 0.f);
                sth(outb + (size_t)(gm0 + rr) * 1024 + gn, f2bf(v));
            }
        }
    }
}

// GRU for one group's rows: uid in [0, 512)
__device__ __forceinline__ void gru_unit(int uid, int tid, int rb,
    const float* __restrict__ gi, const float* __restrict__ gh,
    const float* __restrict__ h, float* __restrict__ hn, short* __restrict__ hnb)
{
    const int i = rb * H_DIMC + uid * 256 + tid;
    const int b = i >> 10, j = i & (H_DIMC - 1);
    const float* gib = gi + (size_t)b * 3 * H_DIMC;
    const float* ghb = gh + (size_t)b * 3 * H_DIMC;
    const float r = 1.f / (1.f + expf(-(ldf(gib + j) + ldf(ghb + j))));
    const float u = 1.f / (1.f + expf(-(ldf(gib + H_DIMC + j) + ldf(ghb + H_DIMC + j))));
    const float n = tanhf(ldf(gib + 2 * H_DIMC + j) + r * ldf(ghb + 2 * H_DIMC + j));
    const float v = (1.f - u) * n + u * ldf(h + i);
    stf(hn + i, v); sth(hnb + i, f2bf(v));
}

// loss for one group's rows (128 samples): uid in [0,192): [0,64) kld, [64,192) nll.
// pointers pre-offset to the group's first row.
__device__ __forceinline__ void loss_unit(int uid, int tid,
    const float* __restrict__ em, const float* __restrict__ es,
    const float* __restrict__ pm, const float* __restrict__ ps,
    const float* __restrict__ xt, const float* __restrict__ dm,
    const float* __restrict__ ds, float* __restrict__ outp, float* sred)
{
    const int KB = 64;  // 128 rows * 128 z / 256 thr
    float v; int target;
    if (uid < KB) {
        const int i = uid * 256 + tid;
        const float esv = ldf(es + i), psv = ldf(ps + i);
        const float dmn = ldf(em + i) - ldf(pm + i);
        v = 0.5f * (2.f * logf(psv + EPSF) - 2.f * logf(esv + EPSF) +
                    (esv * esv + dmn * dmn) / (psv * psv) - 1.f);
        target = 0;
    } else {
        const int i = (uid - KB) * 256 + tid;
        const float d = ldf(ds + i);
        const float diff = xt[i] - ldf(dm + i);
        v = logf(d + EPSF) + HALF_LOG_2PI + diff * diff / (2.f * d * d);
        target = 1;
    }
    for (int o = 32; o > 0; o >>= 1) v += __shfl_down(v, o);
    if ((tid & 63) == 0) sred[tid >> 6] = v;
    __syncthreads();
    if (tid == 0) atomicAdd(outp + target, sred[0] + sred[1] + sred[2] + sred[3]);
    __syncthreads();
}

struct PP {
    const short* xb; const float* x; const float* eps;
    const short *WTpx, *WT1, *WT2, *WTpz, *WT4, *WT56;
    const float *bpx, *benc, *bpr, *bhh, *bem, *bes, *bpz, *bdec, *bih,
                *bpm, *bps, *bdm, *bds;
    float *hf0, *hf1; short *hb0, *hb1;
    short *enc_b, *prior_b, *phi_zb, *dec_b;
    short *phiXb, *phiXs;
    float *ghb, *gib, *pmb, *psb;
    float *kld, *em, *es, *dm, *ds;
    unsigned* bar; int big;
};

// Persistent kernel, TWO independent sample-group pipelines (128 samples each).
// Group g = blocks [g*GBLK, (g+1)*GBLK), own barrier region, own t counter.
// All activation buffers are [B][*] row-indexed -> groups touch disjoint rows.
__global__ __launch_bounds__(256, 3) void vrnn_k(PP p)
{
    __shared__ short smem[24576];
    __shared__ float sred[4];
    const int bid = blockIdx.x, tid = threadIdx.x;
    const int g = bid / GBLK, lbid = bid % GBLK;
    const int rb = g << 7;                 // group row base (128)
    unsigned* bar = p.bar + (size_t)g * BARN;
    const int BIGK = 1 << 30;
    int ph = 0;

    Segs sx;
    sx.s[0] = dseg(1024, 0, 256, p.bpx, 1, nullptr, 0, p.big ? p.phiXb : p.phiXs, 1024);
    sx.s[1] = dsegend(); sx.s[2] = dsegend(); sx.s[3] = dsegend();

    if (p.big) {  // phi_x for this group's rows across all T: 256 m-tiles x 16 n
        for (int u = lbid; u < 256 * 16; u += GBLK) {
            const int mt = u & 255;
            const int bm0 = ((mt >> 1) << 8) + rb + ((mt & 1) << 6);
            gemm_tile(smem, bm0, (u >> 8) << 6,
                      p.xb, 256, p.xb, 256, p.xb, 256, BIGK, BIGK, 1,
                      p.WTpx, 256, sx);
        }
        gridbar(bar, ++ph, lbid);
    }

    for (int t = 0; t < T_DIM; ++t) {
        float* hcur = (t & 1) ? p.hf1 : p.hf0;
        float* hnxt = (t & 1) ? p.hf0 : p.hf1;
        const short* hbc = (t & 1) ? p.hb1 : p.hb0;
        short* hbn = (t & 1) ? p.hb0 : p.hb1;
        const short* phiXt = p.big ? p.phiXb + (size_t)t * B_DIM * H_DIMC : p.phiXs;
        float* em_t = p.em + (size_t)t * B_DIM * Z_DIMC;
        float* es_t = p.es + (size_t)t * B_DIM * Z_DIMC;
        float* dm_t = p.dm + (size_t)t * B_DIM * X_DIMC;
        float* ds_t = p.ds + (size_t)t * B_DIM * X_DIMC;
        const float* eps_t = p.eps + (size_t)t * B_DIM * Z_DIMC;

        if (!p.big) {  // phi_x for this step's group rows: 2 m x 16 n
            for (int u = lbid; u < 32; u += GBLK)
                gemm_tile(smem, (size_t)t * 0 + rb + ((u & 1) << 6), (u >> 1) << 6,
                          p.xb + (size_t)t * B_DIM * X_DIMC, 256,
                          p.xb, 256, p.xb, 256, BIGK, BIGK, 1, p.WTpx, 256, sx);
            gridbar(bar, ++ph, lbid);
        }
        // Stage A: G1 [phiX|h] -> enc | prior | gh ; + loss(t-1). 160 tiles + 192.
        {
            Segs g1;
            g1.s[0] = dseg(1024, 0, 2048, p.benc, 1, nullptr, 0, p.enc_b, 1024);
            g1.s[1] = dseg(2048, 1024, 2048, p.bpr, 1, nullptr, 0, p.prior_b, 1024);
            g1.s[2] = dseg(5120, 1024, 2048, p.bhh, 0, p.ghb, 3 * H_DIMC, nullptr, 0);
            g1.s[3] = dsegend();
            const int tp = t - 1;
            const int nA = 160 + (t > 0 ? 192 : 0);
            for (int u = lbid; u < nA; u += GBLK) {
                if (u < 160)
                    gemm_tile(smem, rb + ((u & 1) << 6), (u >> 1) << 6,
                              phiXt, 1024, hbc, 1024, hbc, 1024, 1024, BIGK, 1,
                              p.WT1, 2048, g1);
                else
                    loss_unit(u - 160, tid,
                              p.em + (size_t)tp * B_DIM * Z_DIMC + (size_t)rb * Z_DIMC,
                              p.es + (size_t)tp * B_DIM * Z_DIMC + (size_t)rb * Z_DIMC,
                              p.pmb + (size_t)rb * Z_DIMC, p.psb + (size_t)rb * Z_DIMC,
                              p.x + (size_t)tp * B_DIM * X_DIMC + (size_t)rb * X_DIMC,
                              p.dm + (size_t)tp * B_DIM * X_DIMC + (size_t)rb * X_DIMC,
                              p.ds + (size_t)tp * B_DIM * X_DIMC + (size_t)rb * X_DIMC,
                              p.kld, sred);
            }
            gridbar(bar, ++ph, lbid);
        }
        // Stage B: G2 enc -> em | es. 8 tiles.
        {
            Segs g2;
            g2.s[0] = dseg(128, 0, 1024, p.bem, 0, em_t, 128, nullptr, 0);
            g2.s[1] = dseg(256, 0, 1024, p.bes, 2, es_t, 128, nullptr, 0);
            g2.s[2] = dsegend(); g2.s[3] = dsegend();
            for (int u = lbid; u < 8; u += GBLK)
                gemm_tile(smem, rb + ((u & 1) << 6), (u >> 1) << 6,
                          p.enc_b, 1024, p.enc_b, 1024, p.enc_b, 1024, BIGK, BIGK, 0,
                          p.WT2, 1024, g2);
            gridbar(bar, ++ph, lbid);
        }
        // Stage C: z -> phi_z. 32 tiles.
        for (int u = lbid; u < 32; u += GBLK)
            z_tile(smem, rb + ((u & 1) << 6), (u >> 1) << 6,
                   em_t, es_t, eps_t, p.WTpz, p.bpz, p.phi_zb);
        gridbar(bar, ++ph, lbid);
        // Stage D: G4 [phiX|phi_z|h] -> dec | gi. 128 tiles.
        {
            Segs g4;
            g4.s[0] = dseg(1024, 1024, 3072, p.bdec, 1, nullptr, 0, p.dec_b, 1024);
            g4.s[1] = dseg(4096, 0, 2048, p.bih, 0, p.gib, 3 * H_DIMC, nullptr, 0);
            g4.s[2] = dsegend(); g4.s[3] = dsegend();
            for (int u = lbid; u < 128; u += GBLK)
                gemm_tile(smem, rb + ((u & 1) << 6), (u >> 1) << 6,
                          phiXt, 1024, p.phi_zb, 1024, hbc, 1024, 1024, 2048, 1,
                          p.WT4, 3072, g4);
            gridbar(bar, ++ph, lbid);
        }
        // Stage E: G56 -> pm|ps|dm|ds ; + GRU. 24 tiles + 512 units.
        {
            Segs g5;
            g5.s[0] = dseg(128, 0, 1024, p.bpm, 0, p.pmb, 128, nullptr, 0);
            g5.s[1] = dseg(256, 0, 1024, p.bps, 2, p.psb, 128, nullptr, 0);
            g5.s[2] = dseg(512, 1024, 2048, p.bdm, 0, dm_t, 256, nullptr, 0);
            g5.s[3] = dseg(768, 1024, 2048, p.bds, 2, ds_t, 256, nullptr, 0);
            for (int u = lbid; u < 24 + 512; u += GBLK) {
                if (u < 24)
                    gemm_tile(smem, rb + ((u & 1) << 6), (u >> 1) << 6,
                              p.prior_b, 1024, p.dec_b, 1024, p.dec_b, 1024,
                              1024, BIGK, 0, p.WT56, 2048, g5);
                else
                    gru_unit(u - 24, tid, rb, p.gib, p.ghb, hcur, hnxt, hbn);
            }
            gridbar(bar, ++ph, lbid);
        }
    }
    // final loss for t = T-1 (per group)
    {
        const int tp = T_DIM - 1;
        for (int u = lbid; u < 192; u += GBLK)
            loss_unit(u, tid,
                      p.em + (size_t)tp * B_DIM * Z_DIMC + (size_t)rb * Z_DIMC,
                      p.es + (size_t)tp * B_DIM * Z_DIMC + (size_t)rb * Z_DIMC,
                      p.pmb + (size_t)rb * Z_DIMC, p.psb + (size_t)rb * Z_DIMC,
                      p.x + (size_t)tp * B_DIM * X_DIMC + (size_t)rb * X_DIMC,
                      p.dm + (size_t)tp * B_DIM * X_DIMC + (size_t)rb * X_DIMC,
                      p.ds + (size_t)tp * B_DIM * X_DIMC + (size_t)rb * X_DIMC,
                      p.kld, sred);
    }
}

// ---- prologue kernels ----
__global__ void packT_k(const float* __restrict__ src, int ldsr,
                        short* __restrict__ dst, int ldd, int n0, int k0)
{
    __shared__ float tile[32][33];
    const int bx = blockIdx.x * 32, by = blockIdx.y * 32;
    const int tx = threadIdx.x, ty = threadIdx.y;  // (32,8)
    for (int i = ty; i < 32; i += 8)
        tile[i][tx] = src[(size_t)(by + i) * ldsr + bx + tx];
    __syncthreads();
    for (int i = ty; i < 32; i += 8)
        dst[(size_t)(n0 + bx + i) * ldd + k0 + by + tx] = f2bf(tile[tx][i]);
}

__global__ void packD_k(const float* __restrict__ src, int ldsr,
                        short* __restrict__ dst, int ldd, int n0, int k0, int kr)
{
    const int idx = blockIdx.x * 256 + threadIdx.x;
    const int n = idx / kr, k = idx % kr;
    dst[(size_t)(n0 + n) * ldd + k0 + k] = f2bf(src[(size_t)n * ldsr + k]);
}

__global__ void cvtx_k(const float* __restrict__ x, short* __restrict__ xb)
{
    const int i = blockIdx.x * 256 + threadIdx.x;
    float4 v = ((const float4*)x)[i];
    short4 s;
    s.x = f2bf(v.x); s.y = f2bf(v.y); s.z = f2bf(v.z); s.w = f2bf(v.w);
    ((short4*)xb)[i] = s;
}

__global__ void hinit_k(const float* __restrict__ h0, float* __restrict__ hf,
                        short* __restrict__ hb)
{
    const int i = blockIdx.x * 256 + threadIdx.x;
    const float v = h0[i];
    hf[i] = v; hb[i] = f2bf(v);
}

__global__ void init_k(unsigned* bar, float* kn)
{
    for (int i = threadIdx.x; i < 2 * BARN; i += 256) bar[i] = 0u;
    if (threadIdx.x < 2) kn[threadIdx.x] = 0.f;
}

extern "C" void kernel_launch(void* const* d_in, const int* in_sizes, int n_in,
                              void* d_out_v, int out_size, void* d_ws, size_t ws_size,
                              hipStream_t stream)
{
    (void)in_sizes; (void)n_in; (void)out_size;
    const float* x    = (const float*)d_in[0];
    const float* h0   = (const float*)d_in[1];
    const float* eps  = (const float*)d_in[2];
    const float* Wpx  = (const float*)d_in[3];
    const float* bpx  = (const float*)d_in[4];
    const float* Wpz  = (const float*)d_in[5];
    const float* bpz  = (const float*)d_in[6];
    const float* Wenc = (const float*)d_in[7];
    const float* benc = (const float*)d_in[8];
    const float* Wem  = (const float*)d_in[9];
    const float* bem  = (const float*)d_in[10];
    const float* Wes  = (const float*)d_in[11];
    const float* bes  = (const float*)d_in[12];
    const float* Wpr  = (const float*)d_in[13];
    const float* bpr  = (const float*)d_in[14];
    const float* Wpm  = (const float*)d_in[15];
    const float* bpm  = (const float*)d_in[16];
    const float* Wps  = (const float*)d_in[17];
    const float* bps  = (const float*)d_in[18];
    const float* Wdec = (const float*)d_in[19];
    const float* bdec = (const float*)d_in[20];
    const float* Wdm  = (const float*)d_in[21];
    const float* bdm  = (const float*)d_in[22];
    const float* Wds  = (const float*)d_in[23];
    const float* bds  = (const float*)d_in[24];
    const float* W_ih = (const float*)d_in[25];
    const float* W_hh = (const float*)d_in[26];
    const float* b_ih = (const float*)d_in[27];
    const float* b_hh = (const float*)d_in[28];

    float* out = (float*)d_out_v;

    char* wsb = (char*)d_ws;
    size_t off = 0;
    auto takeB = [&](size_t bytes) {
        char* p = wsb + off; off += (bytes + 255) & ~(size_t)255; return p;
    };
    short* WTpx = (short*)takeB((size_t)1024 * 256 * 2);
    short* WT1  = (short*)takeB((size_t)5120 * 2048 * 2);
    short* WT2  = (short*)takeB((size_t)256 * 1024 * 2);
    short* WTpz = (short*)takeB((size_t)1024 * 128 * 2);
    short* WT4  = (short*)takeB((size_t)4096 * 3072 * 2);
    short* WT56 = (short*)takeB((size_t)768 * 2048 * 2);
    short* xb   = (short*)takeB((size_t)T_DIM * B_DIM * X_DIMC * 2);
    float* hf0  = (float*)takeB((size_t)B_DIM * H_DIMC * 4);
    float* hf1  = (float*)takeB((size_t)B_DIM * H_DIMC * 4);
    short* hb0  = (short*)takeB((size_t)B_DIM * H_DIMC * 2);
    short* hb1  = (short*)takeB((size_t)B_DIM * H_DIMC * 2);
    short* enc_b   = (short*)takeB((size_t)B_DIM * H_DIMC * 2);
    short* prior_b = (short*)takeB((size_t)B_DIM * H_DIMC * 2);
    short* phi_zb  = (short*)takeB((size_t)B_DIM * H_DIMC * 2);
    short* dec_b   = (short*)takeB((size_t)B_DIM * H_DIMC * 2);
    float* ghb_ = (float*)takeB((size_t)B_DIM * 3 * H_DIMC * 4);
    float* gib_ = (float*)takeB((size_t)B_DIM * 3 * H_DIMC * 4);
    float* pmb  = (float*)takeB((size_t)B_DIM * Z_DIMC * 4);
    float* psb  = (float*)takeB((size_t)B_DIM * Z_DIMC * 4);
    unsigned* bar = (unsigned*)takeB((size_t)2 * BARN * 4);
    const size_t phiXb_bytes = (size_t)T_DIM * B_DIM * H_DIMC * 2;
    const bool big = (off + phiXb_bytes) <= ws_size;
    short* phiXb = big ? (short*)takeB(phiXb_bytes) : nullptr;
    short* phiXs = big ? nullptr : (short*)takeB((size_t)B_DIM * H_DIMC * 2);

    const dim3 tb(256), pt(32, 8);

    // ---- pack weights to bf16 B^T fused layouts ----
    packT_k<<<dim3(32, 8), pt, 0, stream>>>(Wpx, 1024, WTpx, 256, 0, 0);
    packT_k<<<dim3(32, 64), pt, 0, stream>>>(Wenc, 1024, WT1, 2048, 0, 0);
    packT_k<<<dim3(32, 32), pt, 0, stream>>>(Wpr, 1024, WT1, 2048, 1024, 1024);
    packD_k<<<dim3(3072 * 1024 / 256), tb, 0, stream>>>(W_hh, 1024, WT1, 2048, 2048, 1024, 1024);
    packT_k<<<dim3(4, 32), pt, 0, stream>>>(Wem, 128, WT2, 1024, 0, 0);
    packT_k<<<dim3(4, 32), pt, 0, stream>>>(Wes, 128, WT2, 1024, 128, 0);
    packT_k<<<dim3(32, 4), pt, 0, stream>>>(Wpz, 1024, WTpz, 128, 0, 0);
    packT_k<<<dim3(32, 64), pt, 0, stream>>>(Wdec, 1024, WT4, 3072, 0, 1024);
    packD_k<<<dim3(3072 * 2048 / 256), tb, 0, stream>>>(W_ih, 2048, WT4, 3072, 1024, 0, 2048);
    packT_k<<<dim3(4, 32), pt, 0, stream>>>(Wpm, 128, WT56, 2048, 0, 0);
    packT_k<<<dim3(4, 32), pt, 0, stream>>>(Wps, 128, WT56, 2048, 128, 0);
    packT_k<<<dim3(8, 32), pt, 0, stream>>>(Wdm, 256, WT56, 2048, 256, 1024);
    packT_k<<<dim3(8, 32), pt, 0, stream>>>(Wds, 256, WT56, 2048, 512, 1024);

    cvtx_k<<<dim3((size_t)T_DIM * B_DIM * X_DIMC / 4 / 256), tb, 0, stream>>>(x, xb);
    hinit_k<<<dim3(B_DIM * H_DIMC / 256), tb, 0, stream>>>(h0, hf0, hb0);
    init_k<<<1, 256, 0, stream>>>(bar, out);

    PP p;
    p.xb = xb; p.x = x; p.eps = eps;
    p.WTpx = WTpx; p.WT1 = WT1; p.WT2 = WT2; p.WTpz = WTpz; p.WT4 = WT4; p.WT56 = WT56;
    p.bpx = bpx; p.benc = benc; p.bpr = bpr; p.bhh = b_hh; p.bem = bem; p.bes = bes;
    p.bpz = bpz; p.bdec = bdec; p.bih = b_ih; p.bpm = bpm; p.bps = bps;
    p.bdm = bdm; p.bds = bds;
    p.hf0 = hf0; p.hf1 = hf1; p.hb0 = hb0; p.hb1 = hb1;
    p.enc_b = enc_b; p.prior_b = prior_b; p.phi_zb = phi_zb; p.dec_b = dec_b;
    p.phiXb = phiXb; p.phiXs = phiXs;
    p.ghb = ghb_; p.gib = gib_; p.pmb = pmb; p.psb = psb;
    p.kld = out; p.em = out + 2;
    p.es = p.em + (size_t)T_DIM * B_DIM * Z_DIMC;
    p.dm = p.es + (size_t)T_DIM * B_DIM * Z_DIMC;
    p.ds = p.dm + (size_t)T_DIM * B_DIM * X_DIMC;
    p.bar = bar; p.big = big ? 1 : 0;

    vrnn_k<<<dim3(NBLK), tb, 0, stream>>>(p);
}